// Round 1
// baseline (1352.929 us; speedup 1.0000x reference)
//
#include <hip/hip_runtime.h>
#include <stdint.h>

#define B_ROWS 131072
#define SCALE 0.0625f
#define LN_EPS 1e-5f
#define ATTN_EPS 1e-8f

#define BIG_BLOCKS 512
#define BIG_THREADS 512
#define ROWS_PER_BLOCK (B_ROWS / BIG_BLOCKS)   // 256
#define ROWS_PER_WAVE  (ROWS_PER_BLOCK / 8)    // 32 (8 waves/block)
#define NSLICE BIG_BLOCKS                      // 512 partial slices

// ---- workspace layout (float offsets) ----
#define WS_PARTU 0
#define WS_PARTS (WS_PARTU + NSLICE*4096)        // 2097152
#define WS_U     (WS_PARTS + NSLICE*16)          // 2105344
#define WS_S     (WS_U + 4096)                   // 2109440
#define WS_SLOTS (WS_S + 64)                     // 2109504
#define WS_MID   (WS_SLOTS + 4096)               // 2113600
#define WS_GX    (WS_MID + 4096)                 // 2117696
#define WS_GH    (WS_GX + 12288)                 // 2129984
#define WS_H1    (WS_GH + 12288)                 // 2142272
#define WS_QKG   (WS_H1 + 4096)                  // 2146368
#define WS_QB    (WS_QKG + 4096)                 // 2150464
#define WS_WIHV  (WS_QB + 64)                    // 2150528
#define WS_BGX   (WS_WIHV + 196608)              // 2347136
#define WS_WQKG  (WS_BGX + 768)                  // 2347904
#define WS_U2G   (WS_WQKG + 65536)               // 2413440
#define WS_U1    (WS_U2G + 256)                  // 2413696
#define WS_C1    (WS_U1 + 256)                   // 2413952
#define WS_CTR   (WS_C1 + 4)                     // u32 grid-barrier counter
// total ~2413957 floats ~ 9.66 MB

#define SLOT_BLOCKS 128u

// Device-scope grid barrier: monotone counter, phase target passed in.
// Release fetch_add publishes this block's writes (L2 writeback at agent
// scope); relaxed spin + threadfence acquires others' writes (L1/L2 inv).
__device__ __forceinline__ void gridbar(unsigned int* ctr, unsigned int target)
{
  __syncthreads();
  if (threadIdx.x == 0) {
    __threadfence();
    __hip_atomic_fetch_add(ctr, 1u, __ATOMIC_RELEASE, __HIP_MEMORY_SCOPE_AGENT);
    while (__hip_atomic_load(ctr, __ATOMIC_RELAXED, __HIP_MEMORY_SCOPE_AGENT) < target) {
      __builtin_amdgcn_s_sleep(1);
    }
    __threadfence();
  }
  __syncthreads();
}

// =====================================================================
// K_pre1: weight compositions (fp32 inputs)  [unchanged + ctr zero]
// =====================================================================
__global__ __launch_bounds__(256) void k_pre1(
    const float* __restrict__ Wq, const float* __restrict__ bq,
    const float* __restrict__ Wk, const float* __restrict__ bk,
    const float* __restrict__ Wv, const float* __restrict__ bv,
    const float* __restrict__ W_ih, const float* __restrict__ b_ih,
    const float* __restrict__ g_in, const float* __restrict__ be_in,
    float* __restrict__ ws)
{
  int bid = blockIdx.x, t = threadIdx.x;
  if (bid < 48) {
    int j0 = bid * 16;
    float acc[16];
#pragma unroll
    for (int r = 0; r < 16; r++) acc[r] = 0.f;
    int d = t;
    for (int dd = 0; dd < 256; dd++) {
      float v = Wv[dd * 256 + d];
#pragma unroll
      for (int r = 0; r < 16; r++)
        acc[r] = fmaf(W_ih[(j0 + r) * 256 + dd], v, acc[r]);
    }
#pragma unroll
    for (int r = 0; r < 16; r++) ws[WS_WIHV + (j0 + r) * 256 + d] = acc[r];
    if (t < 16) {
      int j = j0 + t;
      float a = b_ih[j];
      for (int dd = 0; dd < 256; dd++)
        a = fmaf(W_ih[j * 256 + dd], bv[dd], a);
      ws[WS_BGX + j] = a;
    }
  } else if (bid < 80) {
    int c0 = (bid - 48) * 8;
    float acc[8];
#pragma unroll
    for (int r = 0; r < 8; r++) acc[r] = 0.f;
    int d = t;
    for (int i = 0; i < 256; i++) {
      float wq = Wq[i * 256 + d];
#pragma unroll
      for (int r = 0; r < 8; r++)
        acc[r] = fmaf(wq, Wk[i * 256 + c0 + r], acc[r]);
    }
#pragma unroll
    for (int r = 0; r < 8; r++) {
      float gc = g_in[c0 + r];
      ws[WS_WQKG + (c0 + r) * 256 + d] = SCALE * gc * acc[r];
    }
    if (t < 8) {
      int c = c0 + t;
      float a = 0.f;
      for (int i = 0; i < 256; i++)
        a = fmaf(bq[i], Wk[i * 256 + c], a);
      ws[WS_U2G + c] = SCALE * g_in[c] * a;
    }
  } else {
    __shared__ __align__(16) float t2[256];
    if (t == 0) *((unsigned int*)(ws + WS_CTR)) = 0u;   // reset grid barrier
    int j = t;
    float a = 0.f;
    for (int dp = 0; dp < 256; dp++)
      a = fmaf(Wk[j * 256 + dp], be_in[dp], a);
    t2[j] = a + bk[j];
    __syncthreads();
    int d = t;
    float u = 0.f;
    for (int i = 0; i < 256; i++)
      u = fmaf(Wq[i * 256 + d], t2[i], u);
    ws[WS_U1 + d] = u;
    if (t == 0) {
      float c = 0.f;
      for (int i = 0; i < 256; i++) c = fmaf(bq[i], t2[i], c);
      ws[WS_C1] = c;
    }
  }
}

// =====================================================================
// K_qkg: initial only (init=1): slots = mu + sigma*noise; s = LN(slots);
//        qkg/qb for iteration 0.  [unchanged]
// =====================================================================
__global__ __launch_bounds__(256) void k_qkg(
    const float* __restrict__ noise, const float* __restrict__ mu,
    const float* __restrict__ sigma, const float* __restrict__ g_s,
    const float* __restrict__ be_s, float* __restrict__ ws, int init)
{
  __shared__ __align__(16) float sS[16 * 260];
  __shared__ __align__(16) float sAux[512];
  __shared__ __align__(16) float sStat[32];
  int bid = blockIdx.x, t = threadIdx.x;
  for (int n = 0; n < 16; n++) {
    float v;
    if (init) v = fmaf(sigma[t], noise[n * 256 + t], mu[t]);
    else      v = ws[WS_SLOTS + n * 256 + t];
    sS[n * 260 + t] = v;
    if (init && bid == 0) ws[WS_SLOTS + n * 256 + t] = v;
  }
  __syncthreads();
  { int n = t >> 4, c = t & 15;
    float s1 = 0.f, s2 = 0.f;
    for (int k = 0; k < 16; k++) {
      float x = sS[n * 260 + c * 16 + k];
      s1 += x; s2 = fmaf(x, x, s2);
    }
    sAux[n * 16 + c] = s1; sAux[256 + n * 16 + c] = s2; }
  __syncthreads();
  if (t < 16) {
    float s1 = 0.f, s2 = 0.f;
    for (int c = 0; c < 16; c++) { s1 += sAux[t * 16 + c]; s2 += sAux[256 + t * 16 + c]; }
    float m = s1 * (1.f / 256.f);
    float v = fmaxf(fmaf(-m, m, s2 * (1.f / 256.f)), 0.f);
    sStat[t] = m; sStat[16 + t] = rsqrtf(v + LN_EPS);
  }
  __syncthreads();
  { float gs = g_s[t], bs = be_s[t];
    for (int n = 0; n < 16; n++) {
      float m = sStat[n], rs = sStat[16 + n];
      sS[n * 260 + t] = fmaf((sS[n * 260 + t] - m) * rs, gs, bs);
    } }
  __syncthreads();
  if (bid < 64) {
    int cr = t >> 6, n = (t >> 2) & 15, ks = t & 3;
    int c = bid * 4 + cr;
    const float* wrow = ws + WS_WQKG + c * 256 + ks * 64;
    const float* srow = &sS[n * 260 + ks * 64];
    float acc = 0.f;
#pragma unroll
    for (int i = 0; i < 16; i++) {
      float4 w = *(const float4*)(wrow + i * 4);
      float4 s4 = *(const float4*)(srow + i * 4);
      acc = fmaf(w.x, s4.x, fmaf(w.y, s4.y, fmaf(w.z, s4.z, fmaf(w.w, s4.w, acc))));
    }
    sAux[t] = acc;
    __syncthreads();
    if (t < 64) {
      int cr2 = t >> 4, n2 = t & 15;
      int c2 = bid * 4 + cr2;
      int b = cr2 * 64 + n2 * 4;
      float s = sAux[b] + sAux[b + 1] + sAux[b + 2] + sAux[b + 3];
      ws[WS_QKG + n2 * 256 + c2] = s + ws[WS_U2G + c2];
    }
  } else {
    int n = t >> 4, ks = t & 15;
    float acc = 0.f;
    for (int k = 0; k < 16; k++)
      acc = fmaf(sS[n * 260 + ks * 16 + k], ws[WS_U1 + ks * 16 + k], acc);
    sAux[t] = acc;
    __syncthreads();
    if (t < 16) {
      float s = 0.f;
      for (int k = 0; k < 16; k++) s += sAux[t * 16 + k];
      ws[WS_QB + t] = SCALE * (s + ws[WS_C1]);
    }
  }
}

// =====================================================================
// K_big: 512 threads (8 waves, 32 rows/wave) -> 4 waves/SIMD occupancy.
// Main loop identical to proven version; epilogue is a two-stage LDS
// reduce in the same 64KB (waves 0-3 store, waves 4-7 RMW-add).
// =====================================================================
__global__ __launch_bounds__(512, 4) void k_big(
    const float* __restrict__ X, float* __restrict__ ws)
{
  __shared__ __align__(16) float red[4 * 4096];   // 64 KB
  __shared__ __align__(16) float redS[128];       // 8 waves x 16
  int t = threadIdx.x;
  int wave = t >> 6, lane = t & 63;
  int p = lane >> 4, g = lane & 15;

  const float* qkg = ws + WS_QKG;
  float qw[4][16];
  float qs[4];
#pragma unroll
  for (int i = 0; i < 4; i++) {
    const float* rp = qkg + (4 * p + i) * 256 + g * 16;
#pragma unroll
    for (int jq = 0; jq < 4; jq++) {
      float4 v4 = *(const float4*)(rp + 4 * jq);
      qw[i][4 * jq + 0] = v4.x; qw[i][4 * jq + 1] = v4.y;
      qw[i][4 * jq + 2] = v4.z; qw[i][4 * jq + 3] = v4.w;
    }
    float s = 0.f;
#pragma unroll
    for (int j = 0; j < 16; j++) s += qw[i][j];
    qs[i] = s;
  }
#pragma unroll
  for (int m = 1; m <= 8; m <<= 1) {
#pragma unroll
    for (int i = 0; i < 4; i++) qs[i] += __shfl_xor(qs[i], m);
  }
  float qb0[4];
  {
    float4 q4 = *(const float4*)(ws + WS_QB + 4 * p);
    qb0[0] = q4.x; qb0[1] = q4.y; qb0[2] = q4.z; qb0[3] = q4.w;
  }

  float P[4][16];
#pragma unroll
  for (int i = 0; i < 4; i++)
#pragma unroll
    for (int j = 0; j < 16; j++) P[i][j] = 0.f;
  float Q[4] = {0.f, 0.f, 0.f, 0.f};
  float Sa[4] = {0.f, 0.f, 0.f, 0.f};

  size_t rowbase = (size_t)blockIdx.x * ROWS_PER_BLOCK + (size_t)wave * ROWS_PER_WAVE;
  const float* cur = X + rowbase * 256 + g * 16;
  float4 va = *(const float4*)cur;
  float4 vb = *(const float4*)(cur + 4);
  float4 vc = *(const float4*)(cur + 8);
  float4 vd = *(const float4*)(cur + 12);

#pragma unroll 1
  for (int r = 0; r < ROWS_PER_WAVE; r++) {
    const float* nxt = (r < ROWS_PER_WAVE - 1) ? (cur + 256) : cur;
    float4 na = *(const float4*)nxt;
    float4 nb = *(const float4*)(nxt + 4);
    float4 nc = *(const float4*)(nxt + 8);
    float4 nd = *(const float4*)(nxt + 12);

    float x[16];
    x[0] = va.x; x[1] = va.y; x[2] = va.z; x[3] = va.w;
    x[4] = vb.x; x[5] = vb.y; x[6] = vb.z; x[7] = vb.w;
    x[8] = vc.x; x[9] = vc.y; x[10] = vc.z; x[11] = vc.w;
    x[12] = vd.x; x[13] = vd.y; x[14] = vd.z; x[15] = vd.w;

    float s1 = 0.f, s2 = 0.f;
#pragma unroll
    for (int j = 0; j < 16; j++) { s1 += x[j]; s2 = fmaf(x[j], x[j], s2); }
#pragma unroll
    for (int m = 1; m <= 8; m <<= 1) {
      s1 += __shfl_xor(s1, m);
      s2 += __shfl_xor(s2, m);
    }
    float mean = s1 * (1.f / 256.f);
    float var = fmaxf(fmaf(-mean, mean, s2 * (1.f / 256.f)), 0.f);
    float rs = rsqrtf(var + LN_EPS);
    float mrs = mean * rs;

    float d0 = 0.f, d1 = 0.f, d2 = 0.f, d3 = 0.f;
#pragma unroll
    for (int j = 0; j < 16; j++) {
      d0 = fmaf(qw[0][j], x[j], d0);
      d1 = fmaf(qw[1][j], x[j], d1);
      d2 = fmaf(qw[2][j], x[j], d2);
      d3 = fmaf(qw[3][j], x[j], d3);
    }
#pragma unroll
    for (int m = 1; m <= 8; m <<= 1) {
      d0 += __shfl_xor(d0, m); d1 += __shfl_xor(d1, m);
      d2 += __shfl_xor(d2, m); d3 += __shfl_xor(d3, m);
    }
    float dsc[4];
    dsc[0] = fmaf(rs, d0, fmaf(-mrs, qs[0], qb0[0]));
    dsc[1] = fmaf(rs, d1, fmaf(-mrs, qs[1], qb0[1]));
    dsc[2] = fmaf(rs, d2, fmaf(-mrs, qs[2], qb0[2]));
    dsc[3] = fmaf(rs, d3, fmaf(-mrs, qs[3], qb0[3]));

    float mx = fmaxf(fmaxf(dsc[0], dsc[1]), fmaxf(dsc[2], dsc[3]));
    mx = fmaxf(mx, __shfl_xor(mx, 16));
    mx = fmaxf(mx, __shfl_xor(mx, 32));
    float e[4];
#pragma unroll
    for (int i = 0; i < 4; i++) e[i] = __expf(dsc[i] - mx);
    float se = e[0] + e[1] + e[2] + e[3];
    se += __shfl_xor(se, 16);
    se += __shfl_xor(se, 32);
    float inv = 1.0f / se;
    float a0[4], ar[4];
#pragma unroll
    for (int i = 0; i < 4; i++) {
      a0[i] = fmaf(e[i], inv, ATTN_EPS);
      ar[i] = a0[i] * rs;
    }
#pragma unroll
    for (int j = 0; j < 16; j++) {
      P[0][j] = fmaf(ar[0], x[j], P[0][j]);
      P[1][j] = fmaf(ar[1], x[j], P[1][j]);
      P[2][j] = fmaf(ar[2], x[j], P[2][j]);
      P[3][j] = fmaf(ar[3], x[j], P[3][j]);
    }
#pragma unroll
    for (int i = 0; i < 4; i++) {
      Q[i] = fmaf(a0[i], mrs, Q[i]);
      Sa[i] += a0[i];
    }
    va = na; vb = nb; vc = nc; vd = nd; cur = nxt;
  }

  // Two-stage cross-wave reduce in 64KB LDS (Uy = P - Q per slot/elem).
  int slot = wave & 3;
  if (wave < 4) {
#pragma unroll
    for (int i = 0; i < 4; i++) {
#pragma unroll
      for (int jq = 0; jq < 4; jq++) {
        float4 v4;
        v4.x = P[i][4 * jq + 0] - Q[i]; v4.y = P[i][4 * jq + 1] - Q[i];
        v4.z = P[i][4 * jq + 2] - Q[i]; v4.w = P[i][4 * jq + 3] - Q[i];
        *(float4*)&red[slot * 4096 + (4 * p + i) * 256 + g * 16 + jq * 4] = v4;
      }
    }
  }
  if (g == 0) {
#pragma unroll
    for (int i = 0; i < 4; i++) redS[wave * 16 + 4 * p + i] = Sa[i];
  }
  __syncthreads();
  if (wave >= 4) {
#pragma unroll
    for (int i = 0; i < 4; i++) {
#pragma unroll
      for (int jq = 0; jq < 4; jq++) {
        float4* dst = (float4*)&red[slot * 4096 + (4 * p + i) * 256 + g * 16 + jq * 4];
        float4 c = *dst;
        c.x += P[i][4 * jq + 0] - Q[i]; c.y += P[i][4 * jq + 1] - Q[i];
        c.z += P[i][4 * jq + 2] - Q[i]; c.w += P[i][4 * jq + 3] - Q[i];
        *dst = c;
      }
    }
  }
  __syncthreads();
#pragma unroll
  for (int k = 0; k < 8; k++) {
    int idx = k * 512 + t;
    float v = red[idx] + red[4096 + idx] + red[8192 + idx] + red[12288 + idx];
    ws[WS_PARTU + (size_t)blockIdx.x * 4096 + idx] = v;
  }
  if (t < 16) {
    float sv = 0.f;
#pragma unroll
    for (int w = 0; w < 8; w++) sv += redS[w * 16 + t];
    ws[WS_PARTS + blockIdx.x * 16 + t] = sv;
  }
}

// =====================================================================
// K_slot: fused slot-side chain for one iteration, 128 blocks x 256 thr.
// phase0 red -> bar -> phase1 gxgh -> bar -> phase2 midh1 -> bar ->
// phase3 ffnew -> bar -> phase4 qkg (skipped on last iter).
// =====================================================================
__global__ __launch_bounds__(256) void k_slot(
    const float* __restrict__ W_hh, const float* __restrict__ b_hh,
    const float* __restrict__ g_in, const float* __restrict__ be_in,
    const float* __restrict__ W1, const float* __restrict__ b1,
    const float* __restrict__ g_f, const float* __restrict__ be_f,
    const float* __restrict__ W2, const float* __restrict__ b2v,
    const float* __restrict__ g_s, const float* __restrict__ be_s,
    float* __restrict__ out, float* __restrict__ ws, int it)
{
  __shared__ __align__(16) float smem[4704];  // 18.4 KB, aliased per phase
  float* sBuf  = smem;            // 16*260
  float* sAux  = smem + 4160;     // 512
  float* sStat = smem + 4672;     // 32
  int bid = blockIdx.x, t = threadIdx.x;
  unsigned int* ctr = (unsigned int*)(ws + WS_CTR);
  unsigned int base = (unsigned int)it * 4u * SLOT_BLOCKS;

  // ---- phase 0: reduce 512 partial slices -> U[16][256], S[16] ----
  {
    int le = t & 31, grp = t >> 5;                 // 8 groups of 32
    int e = bid * 32 + le;
    float acc = 0.f;
#pragma unroll 8
    for (int k = 0; k < 64; k++)
      acc += ws[WS_PARTU + (size_t)(grp + k * 8) * 4096 + e];
    sAux[t] = acc;
    __syncthreads();
    if (t < 32) {
      float s = 0.f;
#pragma unroll
      for (int w = 0; w < 8; w++) s += sAux[w * 32 + t];
      ws[WS_U + bid * 32 + t] = s;
    }
    if (bid == 0) {
      int n = t & 15, g16 = t >> 4;                // 16 groups of 16
      float a2 = 0.f;
#pragma unroll 8
      for (int k = 0; k < 32; k++)
        a2 += ws[WS_PARTS + (g16 + k * 16) * 16 + n];
      __syncthreads();
      sAux[t] = a2;
      __syncthreads();
      if (t < 16) {
        float s = 0.f;
#pragma unroll
        for (int w = 0; w < 16; w++) s += sAux[w * 16 + t];
        ws[WS_S + t] = s;
      }
    }
  }
  gridbar(ctr, base + SLOT_BLOCKS);

  // ---- phase 1: gx (bid<64) / gh (bid>=64) ----
  {
    bool isgx = bid < 64;
    float* sU = sBuf;
    float* sInv = sStat;
    if (isgx && t < 16) sInv[t] = 1.0f / ws[WS_S + t];
    __syncthreads();
    if (isgx) {
      float gi = g_in[t], bi = be_in[t];
      for (int n = 0; n < 16; n++)
        sU[n * 260 + t] = fmaf(gi * ws[WS_U + n * 256 + t], sInv[n], bi);
    } else {
      for (int n = 0; n < 16; n++)
        sU[n * 260 + t] = ws[WS_SLOTS + n * 256 + t];
    }
    __syncthreads();
    int jr = t >> 4, n = t & 15;
    if (jr < 12) {
      int j = (isgx ? bid : bid - 64) * 12 + jr;
      const float* srow = &sU[n * 260];
      const float* wrow = isgx ? (ws + WS_WIHV + j * 256) : (W_hh + j * 256);
      float acc = isgx ? ws[WS_BGX + j] : b_hh[j];
#pragma unroll 8
      for (int k = 0; k < 64; k++) {
        float4 w = *(const float4*)(wrow + k * 4);
        float4 s4 = *(const float4*)(srow + k * 4);
        acc = fmaf(w.x, s4.x, fmaf(w.y, s4.y, fmaf(w.z, s4.z, fmaf(w.w, s4.w, acc))));
      }
      if (isgx) ws[WS_GX + n * 768 + j] = acc;
      else      ws[WS_GH + n * 768 + j] = acc;
    }
  }
  gridbar(ctr, base + 2 * SLOT_BLOCKS);

  // ---- phase 2: GRU gates -> mid; LN(g_f); h1 = relu(lnf@W1.T+b1) ----
  if (bid < 64) {
    float* sM = sBuf;
    for (int n = 0; n < 16; n++) {
      float xr = ws[WS_GX + n * 768 + t],       hr = ws[WS_GH + n * 768 + t];
      float xz = ws[WS_GX + n * 768 + 256 + t], hz = ws[WS_GH + n * 768 + 256 + t];
      float xn = ws[WS_GX + n * 768 + 512 + t], hn = ws[WS_GH + n * 768 + 512 + t];
      float sp = ws[WS_SLOTS + n * 256 + t];
      float r = 1.f / (1.f + __expf(-(xr + hr)));
      float z = 1.f / (1.f + __expf(-(xz + hz)));
      float nn = tanhf(fmaf(r, hn, xn));
      float mid = fmaf(z, sp - nn, nn);
      sM[n * 260 + t] = mid;
      if (bid == 0) ws[WS_MID + n * 256 + t] = mid;
    }
    __syncthreads();
    { int n = t >> 4, c = t & 15;
      float s1 = 0.f, s2 = 0.f;
      for (int k = 0; k < 16; k++) {
        float x = sM[n * 260 + c * 16 + k];
        s1 += x; s2 = fmaf(x, x, s2);
      }
      sAux[n * 16 + c] = s1; sAux[256 + n * 16 + c] = s2; }
    __syncthreads();
    if (t < 16) {
      float s1 = 0.f, s2 = 0.f;
      for (int c = 0; c < 16; c++) { s1 += sAux[t * 16 + c]; s2 += sAux[256 + t * 16 + c]; }
      float m = s1 * (1.f / 256.f);
      float v = fmaxf(fmaf(-m, m, s2 * (1.f / 256.f)), 0.f);
      sStat[t] = m; sStat[16 + t] = rsqrtf(v + LN_EPS);
    }
    __syncthreads();
    { float gf = g_f[t], bf = be_f[t];
      for (int n = 0; n < 16; n++) {
        float m = sStat[n], rs = sStat[16 + n];
        sM[n * 260 + t] = fmaf((sM[n * 260 + t] - m) * rs, gf, bf);
      } }
    __syncthreads();
    int jr = t >> 6, n = (t >> 2) & 15, ks = t & 3;
    int j = bid * 4 + jr;
    const float* wrow = W1 + j * 256 + ks * 64;
    const float* srow = &sM[n * 260 + ks * 64];
    float acc = 0.f;
#pragma unroll
    for (int k = 0; k < 16; k++) {
      float4 w = *(const float4*)(wrow + k * 4);
      float4 s4 = *(const float4*)(srow + k * 4);
      acc = fmaf(w.x, s4.x, fmaf(w.y, s4.y, fmaf(w.z, s4.z, fmaf(w.w, s4.w, acc))));
    }
    sAux[t] = acc;
    __syncthreads();
    if (t < 64) {
      int jr2 = t >> 4, n2 = t & 15;
      int j2 = bid * 4 + jr2;
      int b = jr2 * 64 + n2 * 4;
      float s = sAux[b] + sAux[b + 1] + sAux[b + 2] + sAux[b + 3] + b1[j2];
      ws[WS_H1 + n2 * 256 + j2] = fmaxf(s, 0.f);
    }
  }
  gridbar(ctr, base + 3 * SLOT_BLOCKS);

  // ---- phase 3: ff = h1@W2.T + b2; slots = mid + ff -> ws.slots, out ----
  if (bid < 64) {
    float* sH = sBuf;
    for (int n = 0; n < 16; n++)
      sH[n * 260 + t] = ws[WS_H1 + n * 256 + t];
    __syncthreads();
    int dr = t >> 6, n = (t >> 2) & 15, ks = t & 3;
    int d = bid * 4 + dr;
    const float* wrow = W2 + d * 256 + ks * 64;
    const float* srow = &sH[n * 260 + ks * 64];
    float acc = 0.f;
#pragma unroll
    for (int k = 0; k < 16; k++) {
      float4 w = *(const float4*)(wrow + k * 4);
      float4 s4 = *(const float4*)(srow + k * 4);
      acc = fmaf(w.x, s4.x, fmaf(w.y, s4.y, fmaf(w.z, s4.z, fmaf(w.w, s4.w, acc))));
    }
    sAux[t] = acc;
    __syncthreads();
    if (t < 64) {
      int dr2 = t >> 4, n2 = t & 15;
      int d2 = bid * 4 + dr2;
      int b = dr2 * 64 + n2 * 4;
      float s = sAux[b] + sAux[b + 1] + sAux[b + 2] + sAux[b + 3]
              + b2v[d2] + ws[WS_MID + n2 * 256 + d2];
      ws[WS_SLOTS + n2 * 256 + d2] = s;
      out[n2 * 256 + d2] = s;
    }
  }
  gridbar(ctr, base + 4 * SLOT_BLOCKS);

  // ---- phase 4: qkg/qb for next iteration (skip on last iter) ----
  if (it < 2 && bid <= 64) {
    float* sS = sBuf;
    for (int n = 0; n < 16; n++)
      sS[n * 260 + t] = ws[WS_SLOTS + n * 256 + t];
    __syncthreads();
    { int n = t >> 4, c = t & 15;
      float s1 = 0.f, s2 = 0.f;
      for (int k = 0; k < 16; k++) {
        float x = sS[n * 260 + c * 16 + k];
        s1 += x; s2 = fmaf(x, x, s2);
      }
      sAux[n * 16 + c] = s1; sAux[256 + n * 16 + c] = s2; }
    __syncthreads();
    if (t < 16) {
      float s1 = 0.f, s2 = 0.f;
      for (int c = 0; c < 16; c++) { s1 += sAux[t * 16 + c]; s2 += sAux[256 + t * 16 + c]; }
      float m = s1 * (1.f / 256.f);
      float v = fmaxf(fmaf(-m, m, s2 * (1.f / 256.f)), 0.f);
      sStat[t] = m; sStat[16 + t] = rsqrtf(v + LN_EPS);
    }
    __syncthreads();
    { float gs = g_s[t], bs = be_s[t];
      for (int n = 0; n < 16; n++) {
        float m = sStat[n], rs = sStat[16 + n];
        sS[n * 260 + t] = fmaf((sS[n * 260 + t] - m) * rs, gs, bs);
      } }
    __syncthreads();
    if (bid < 64) {
      int cr = t >> 6, n = (t >> 2) & 15, ks = t & 3;
      int c = bid * 4 + cr;
      const float* wrow = ws + WS_WQKG + c * 256 + ks * 64;
      const float* srow = &sS[n * 260 + ks * 64];
      float acc = 0.f;
#pragma unroll
      for (int i = 0; i < 16; i++) {
        float4 w = *(const float4*)(wrow + i * 4);
        float4 s4 = *(const float4*)(srow + i * 4);
        acc = fmaf(w.x, s4.x, fmaf(w.y, s4.y, fmaf(w.z, s4.z, fmaf(w.w, s4.w, acc))));
      }
      sAux[t] = acc;
      __syncthreads();
      if (t < 64) {
        int cr2 = t >> 4, n2 = t & 15;
        int c2 = bid * 4 + cr2;
        int b = cr2 * 64 + n2 * 4;
        float s = sAux[b] + sAux[b + 1] + sAux[b + 2] + sAux[b + 3];
        ws[WS_QKG + n2 * 256 + c2] = s + ws[WS_U2G + c2];
      }
    } else {
      int n = t >> 4, ks = t & 15;
      float acc = 0.f;
      for (int k = 0; k < 16; k++)
        acc = fmaf(sS[n * 260 + ks * 16 + k], ws[WS_U1 + ks * 16 + k], acc);
      sAux[t] = acc;
      __syncthreads();
      if (t < 16) {
        float s = 0.f;
        for (int k = 0; k < 16; k++) s += sAux[t * 16 + k];
        ws[WS_QB + t] = SCALE * (s + ws[WS_C1]);
      }
    }
  }
}

// =====================================================================
extern "C" void kernel_launch(void* const* d_in, const int* in_sizes, int n_in,
                              void* d_out, int out_size, void* d_ws, size_t ws_size,
                              hipStream_t stream)
{
  (void)in_sizes; (void)n_in; (void)out_size; (void)ws_size;
  const float* inputs = (const float*)d_in[0];
  const float* noise  = (const float*)d_in[1];
  const float* mu     = (const float*)d_in[2];
  const float* sigma  = (const float*)d_in[3];
  const float* Wq     = (const float*)d_in[4];
  const float* bq     = (const float*)d_in[5];
  const float* Wk     = (const float*)d_in[6];
  const float* bk     = (const float*)d_in[7];
  const float* Wv     = (const float*)d_in[8];
  const float* bv     = (const float*)d_in[9];
  const float* W_ih   = (const float*)d_in[10];
  const float* W_hh   = (const float*)d_in[11];
  const float* b_ih   = (const float*)d_in[12];
  const float* b_hh   = (const float*)d_in[13];
  const float* W1     = (const float*)d_in[14];
  const float* b1     = (const float*)d_in[15];
  const float* W2     = (const float*)d_in[16];
  const float* b2     = (const float*)d_in[17];
  const float* g_in   = (const float*)d_in[18];
  const float* be_in  = (const float*)d_in[19];
  const float* g_s    = (const float*)d_in[20];
  const float* be_s   = (const float*)d_in[21];
  const float* g_f    = (const float*)d_in[22];
  const float* be_f   = (const float*)d_in[23];
  float* ws = (float*)d_ws;
  float* out = (float*)d_out;

  hipLaunchKernelGGL(k_pre1, dim3(81), dim3(256), 0, stream,
                     Wq, bq, Wk, bk, Wv, bv, W_ih, b_ih, g_in, be_in, ws);
  hipLaunchKernelGGL(k_qkg, dim3(65), dim3(256), 0, stream,
                     noise, mu, sigma, g_s, be_s, ws, 1);
  for (int it = 0; it < 3; it++) {
    hipLaunchKernelGGL(k_big, dim3(BIG_BLOCKS), dim3(BIG_THREADS), 0, stream, inputs, ws);
    hipLaunchKernelGGL(k_slot, dim3(SLOT_BLOCKS), dim3(256), 0, stream,
                       W_hh, b_hh, g_in, be_in, W1, b1, g_f, be_f,
                       W2, b2, g_s, be_s, out, ws, it);
  }
}

// Round 2
// 748.668 us; speedup vs baseline: 1.8071x; 1.8071x over previous
//
#include <hip/hip_runtime.h>
#include <stdint.h>

#define B_ROWS 131072
#define SCALE 0.0625f
#define LN_EPS 1e-5f
#define ATTN_EPS 1e-8f

#define BIG_BLOCKS 512
#define BIG_THREADS 512
#define ROWS_PER_BLOCK (B_ROWS / BIG_BLOCKS)   // 256
#define ROWS_PER_WAVE  (ROWS_PER_BLOCK / 8)    // 32 (8 waves/block)
#define NSLICE BIG_BLOCKS                      // 512 partial slices

// ---- workspace layout (float offsets) ----
#define WS_PARTU 0
#define WS_PARTS (WS_PARTU + NSLICE*4096)        // 2097152
#define WS_U     (WS_PARTS + NSLICE*16)          // 2105344
#define WS_S     (WS_U + 4096)                   // 2109440
#define WS_SLOTS (WS_S + 64)                     // 2109504
#define WS_MID   (WS_SLOTS + 4096)               // 2113600
#define WS_GX    (WS_MID + 4096)                 // 2117696
#define WS_GH    (WS_GX + 12288)                 // 2129984
#define WS_H1    (WS_GH + 12288)                 // 2142272
#define WS_QKG   (WS_H1 + 4096)                  // 2146368
#define WS_QB    (WS_QKG + 4096)                 // 2150464
#define WS_WIHV  (WS_QB + 64)                    // 2150528
#define WS_BGX   (WS_WIHV + 196608)              // 2347136
#define WS_WQKG  (WS_BGX + 768)                  // 2347904
#define WS_U2G   (WS_WQKG + 65536)               // 2413440
#define WS_U1    (WS_U2G + 256)                  // 2413696
#define WS_C1    (WS_U1 + 256)                   // 2413952
#define WS_CTR   (WS_C1 + 4)                     // u32 grid-barrier counter
// total ~2413957 floats ~ 9.66 MB

#define SLOT_BLOCKS 128u

// Device-scope grid barrier: monotone counter, phase target passed in.
__device__ __forceinline__ void gridbar(unsigned int* ctr, unsigned int target)
{
  __syncthreads();
  if (threadIdx.x == 0) {
    __threadfence();
    __hip_atomic_fetch_add(ctr, 1u, __ATOMIC_RELEASE, __HIP_MEMORY_SCOPE_AGENT);
    while (__hip_atomic_load(ctr, __ATOMIC_RELAXED, __HIP_MEMORY_SCOPE_AGENT) < target) {
      __builtin_amdgcn_s_sleep(1);
    }
    __threadfence();
  }
  __syncthreads();
}

// =====================================================================
// K_pre1: weight compositions (fp32 inputs)  [unchanged + ctr zero]
// =====================================================================
__global__ __launch_bounds__(256) void k_pre1(
    const float* __restrict__ Wq, const float* __restrict__ bq,
    const float* __restrict__ Wk, const float* __restrict__ bk,
    const float* __restrict__ Wv, const float* __restrict__ bv,
    const float* __restrict__ W_ih, const float* __restrict__ b_ih,
    const float* __restrict__ g_in, const float* __restrict__ be_in,
    float* __restrict__ ws)
{
  int bid = blockIdx.x, t = threadIdx.x;
  if (bid < 48) {
    int j0 = bid * 16;
    float acc[16];
#pragma unroll
    for (int r = 0; r < 16; r++) acc[r] = 0.f;
    int d = t;
    for (int dd = 0; dd < 256; dd++) {
      float v = Wv[dd * 256 + d];
#pragma unroll
      for (int r = 0; r < 16; r++)
        acc[r] = fmaf(W_ih[(j0 + r) * 256 + dd], v, acc[r]);
    }
#pragma unroll
    for (int r = 0; r < 16; r++) ws[WS_WIHV + (j0 + r) * 256 + d] = acc[r];
    if (t < 16) {
      int j = j0 + t;
      float a = b_ih[j];
      for (int dd = 0; dd < 256; dd++)
        a = fmaf(W_ih[j * 256 + dd], bv[dd], a);
      ws[WS_BGX + j] = a;
    }
  } else if (bid < 80) {
    int c0 = (bid - 48) * 8;
    float acc[8];
#pragma unroll
    for (int r = 0; r < 8; r++) acc[r] = 0.f;
    int d = t;
    for (int i = 0; i < 256; i++) {
      float wq = Wq[i * 256 + d];
#pragma unroll
      for (int r = 0; r < 8; r++)
        acc[r] = fmaf(wq, Wk[i * 256 + c0 + r], acc[r]);
    }
#pragma unroll
    for (int r = 0; r < 8; r++) {
      float gc = g_in[c0 + r];
      ws[WS_WQKG + (c0 + r) * 256 + d] = SCALE * gc * acc[r];
    }
    if (t < 8) {
      int c = c0 + t;
      float a = 0.f;
      for (int i = 0; i < 256; i++)
        a = fmaf(bq[i], Wk[i * 256 + c], a);
      ws[WS_U2G + c] = SCALE * g_in[c] * a;
    }
  } else {
    __shared__ __align__(16) float t2[256];
    if (t == 0) *((unsigned int*)(ws + WS_CTR)) = 0u;   // reset grid barrier
    int j = t;
    float a = 0.f;
    for (int dp = 0; dp < 256; dp++)
      a = fmaf(Wk[j * 256 + dp], be_in[dp], a);
    t2[j] = a + bk[j];
    __syncthreads();
    int d = t;
    float u = 0.f;
    for (int i = 0; i < 256; i++)
      u = fmaf(Wq[i * 256 + d], t2[i], u);
    ws[WS_U1 + d] = u;
    if (t == 0) {
      float c = 0.f;
      for (int i = 0; i < 256; i++) c = fmaf(bq[i], t2[i], c);
      ws[WS_C1] = c;
    }
  }
}

// =====================================================================
// K_qkg: initial only (init=1): slots = mu + sigma*noise; s = LN(slots);
//        qkg/qb for iteration 0.  [unchanged]
// =====================================================================
__global__ __launch_bounds__(256) void k_qkg(
    const float* __restrict__ noise, const float* __restrict__ mu,
    const float* __restrict__ sigma, const float* __restrict__ g_s,
    const float* __restrict__ be_s, float* __restrict__ ws, int init)
{
  __shared__ __align__(16) float sS[16 * 260];
  __shared__ __align__(16) float sAux[512];
  __shared__ __align__(16) float sStat[32];
  int bid = blockIdx.x, t = threadIdx.x;
  for (int n = 0; n < 16; n++) {
    float v;
    if (init) v = fmaf(sigma[t], noise[n * 256 + t], mu[t]);
    else      v = ws[WS_SLOTS + n * 256 + t];
    sS[n * 260 + t] = v;
    if (init && bid == 0) ws[WS_SLOTS + n * 256 + t] = v;
  }
  __syncthreads();
  { int n = t >> 4, c = t & 15;
    float s1 = 0.f, s2 = 0.f;
    for (int k = 0; k < 16; k++) {
      float x = sS[n * 260 + c * 16 + k];
      s1 += x; s2 = fmaf(x, x, s2);
    }
    sAux[n * 16 + c] = s1; sAux[256 + n * 16 + c] = s2; }
  __syncthreads();
  if (t < 16) {
    float s1 = 0.f, s2 = 0.f;
    for (int c = 0; c < 16; c++) { s1 += sAux[t * 16 + c]; s2 += sAux[256 + t * 16 + c]; }
    float m = s1 * (1.f / 256.f);
    float v = fmaxf(fmaf(-m, m, s2 * (1.f / 256.f)), 0.f);
    sStat[t] = m; sStat[16 + t] = rsqrtf(v + LN_EPS);
  }
  __syncthreads();
  { float gs = g_s[t], bs = be_s[t];
    for (int n = 0; n < 16; n++) {
      float m = sStat[n], rs = sStat[16 + n];
      sS[n * 260 + t] = fmaf((sS[n * 260 + t] - m) * rs, gs, bs);
    } }
  __syncthreads();
  if (bid < 64) {
    int cr = t >> 6, n = (t >> 2) & 15, ks = t & 3;
    int c = bid * 4 + cr;
    const float* wrow = ws + WS_WQKG + c * 256 + ks * 64;
    const float* srow = &sS[n * 260 + ks * 64];
    float acc = 0.f;
#pragma unroll
    for (int i = 0; i < 16; i++) {
      float4 w = *(const float4*)(wrow + i * 4);
      float4 s4 = *(const float4*)(srow + i * 4);
      acc = fmaf(w.x, s4.x, fmaf(w.y, s4.y, fmaf(w.z, s4.z, fmaf(w.w, s4.w, acc))));
    }
    sAux[t] = acc;
    __syncthreads();
    if (t < 64) {
      int cr2 = t >> 4, n2 = t & 15;
      int c2 = bid * 4 + cr2;
      int b = cr2 * 64 + n2 * 4;
      float s = sAux[b] + sAux[b + 1] + sAux[b + 2] + sAux[b + 3];
      ws[WS_QKG + n2 * 256 + c2] = s + ws[WS_U2G + c2];
    }
  } else {
    int n = t >> 4, ks = t & 15;
    float acc = 0.f;
    for (int k = 0; k < 16; k++)
      acc = fmaf(sS[n * 260 + ks * 16 + k], ws[WS_U1 + ks * 16 + k], acc);
    sAux[t] = acc;
    __syncthreads();
    if (t < 16) {
      float s = 0.f;
      for (int k = 0; k < 16; k++) s += sAux[t * 16 + k];
      ws[WS_QB + t] = SCALE * (s + ws[WS_C1]);
    }
  }
}

// =====================================================================
// K_big: 512 threads (8 waves, 32 rows/wave). launch_bounds(512,2):
// VGPR budget ~128 -> compiler's natural ~96-100, no spills; HW still
// schedules 2 blocks/CU (LDS 66KB) = 16 waves/CU = 4 waves/SIMD.
// (512,4) capped VGPR at 64 -> scratch spills, FETCH 952MB. Never again.
// =====================================================================
__global__ __launch_bounds__(512, 2) void k_big(
    const float* __restrict__ X, float* __restrict__ ws)
{
  __shared__ __align__(16) float red[4 * 4096];   // 64 KB
  __shared__ __align__(16) float redS[128];       // 8 waves x 16
  int t = threadIdx.x;
  int wave = t >> 6, lane = t & 63;
  int p = lane >> 4, g = lane & 15;

  const float* qkg = ws + WS_QKG;
  float qw[4][16];
  float qs[4];
#pragma unroll
  for (int i = 0; i < 4; i++) {
    const float* rp = qkg + (4 * p + i) * 256 + g * 16;
#pragma unroll
    for (int jq = 0; jq < 4; jq++) {
      float4 v4 = *(const float4*)(rp + 4 * jq);
      qw[i][4 * jq + 0] = v4.x; qw[i][4 * jq + 1] = v4.y;
      qw[i][4 * jq + 2] = v4.z; qw[i][4 * jq + 3] = v4.w;
    }
    float s = 0.f;
#pragma unroll
    for (int j = 0; j < 16; j++) s += qw[i][j];
    qs[i] = s;
  }
#pragma unroll
  for (int m = 1; m <= 8; m <<= 1) {
#pragma unroll
    for (int i = 0; i < 4; i++) qs[i] += __shfl_xor(qs[i], m);
  }
  float qb0[4];
  {
    float4 q4 = *(const float4*)(ws + WS_QB + 4 * p);
    qb0[0] = q4.x; qb0[1] = q4.y; qb0[2] = q4.z; qb0[3] = q4.w;
  }

  float P[4][16];
#pragma unroll
  for (int i = 0; i < 4; i++)
#pragma unroll
    for (int j = 0; j < 16; j++) P[i][j] = 0.f;
  float Q[4] = {0.f, 0.f, 0.f, 0.f};
  float Sa[4] = {0.f, 0.f, 0.f, 0.f};

  size_t rowbase = (size_t)blockIdx.x * ROWS_PER_BLOCK + (size_t)wave * ROWS_PER_WAVE;
  const float* cur = X + rowbase * 256 + g * 16;
  float4 va = *(const float4*)cur;
  float4 vb = *(const float4*)(cur + 4);
  float4 vc = *(const float4*)(cur + 8);
  float4 vd = *(const float4*)(cur + 12);

#pragma unroll 1
  for (int r = 0; r < ROWS_PER_WAVE; r++) {
    const float* nxt = (r < ROWS_PER_WAVE - 1) ? (cur + 256) : cur;
    float4 na = *(const float4*)nxt;
    float4 nb = *(const float4*)(nxt + 4);
    float4 nc = *(const float4*)(nxt + 8);
    float4 nd = *(const float4*)(nxt + 12);

    float x[16];
    x[0] = va.x; x[1] = va.y; x[2] = va.z; x[3] = va.w;
    x[4] = vb.x; x[5] = vb.y; x[6] = vb.z; x[7] = vb.w;
    x[8] = vc.x; x[9] = vc.y; x[10] = vc.z; x[11] = vc.w;
    x[12] = vd.x; x[13] = vd.y; x[14] = vd.z; x[15] = vd.w;

    float s1 = 0.f, s2 = 0.f;
#pragma unroll
    for (int j = 0; j < 16; j++) { s1 += x[j]; s2 = fmaf(x[j], x[j], s2); }
#pragma unroll
    for (int m = 1; m <= 8; m <<= 1) {
      s1 += __shfl_xor(s1, m);
      s2 += __shfl_xor(s2, m);
    }
    float mean = s1 * (1.f / 256.f);
    float var = fmaxf(fmaf(-mean, mean, s2 * (1.f / 256.f)), 0.f);
    float rs = rsqrtf(var + LN_EPS);
    float mrs = mean * rs;

    float d0 = 0.f, d1 = 0.f, d2 = 0.f, d3 = 0.f;
#pragma unroll
    for (int j = 0; j < 16; j++) {
      d0 = fmaf(qw[0][j], x[j], d0);
      d1 = fmaf(qw[1][j], x[j], d1);
      d2 = fmaf(qw[2][j], x[j], d2);
      d3 = fmaf(qw[3][j], x[j], d3);
    }
#pragma unroll
    for (int m = 1; m <= 8; m <<= 1) {
      d0 += __shfl_xor(d0, m); d1 += __shfl_xor(d1, m);
      d2 += __shfl_xor(d2, m); d3 += __shfl_xor(d3, m);
    }
    float dsc[4];
    dsc[0] = fmaf(rs, d0, fmaf(-mrs, qs[0], qb0[0]));
    dsc[1] = fmaf(rs, d1, fmaf(-mrs, qs[1], qb0[1]));
    dsc[2] = fmaf(rs, d2, fmaf(-mrs, qs[2], qb0[2]));
    dsc[3] = fmaf(rs, d3, fmaf(-mrs, qs[3], qb0[3]));

    float mx = fmaxf(fmaxf(dsc[0], dsc[1]), fmaxf(dsc[2], dsc[3]));
    mx = fmaxf(mx, __shfl_xor(mx, 16));
    mx = fmaxf(mx, __shfl_xor(mx, 32));
    float e[4];
#pragma unroll
    for (int i = 0; i < 4; i++) e[i] = __expf(dsc[i] - mx);
    float se = e[0] + e[1] + e[2] + e[3];
    se += __shfl_xor(se, 16);
    se += __shfl_xor(se, 32);
    float inv = 1.0f / se;
    float a0[4], ar[4];
#pragma unroll
    for (int i = 0; i < 4; i++) {
      a0[i] = fmaf(e[i], inv, ATTN_EPS);
      ar[i] = a0[i] * rs;
    }
#pragma unroll
    for (int j = 0; j < 16; j++) {
      P[0][j] = fmaf(ar[0], x[j], P[0][j]);
      P[1][j] = fmaf(ar[1], x[j], P[1][j]);
      P[2][j] = fmaf(ar[2], x[j], P[2][j]);
      P[3][j] = fmaf(ar[3], x[j], P[3][j]);
    }
#pragma unroll
    for (int i = 0; i < 4; i++) {
      Q[i] = fmaf(a0[i], mrs, Q[i]);
      Sa[i] += a0[i];
    }
    va = na; vb = nb; vc = nc; vd = nd; cur = nxt;
  }

  // Two-stage cross-wave reduce in 64KB LDS (Uy = P - Q per slot/elem).
  int slot = wave & 3;
  if (wave < 4) {
#pragma unroll
    for (int i = 0; i < 4; i++) {
#pragma unroll
      for (int jq = 0; jq < 4; jq++) {
        float4 v4;
        v4.x = P[i][4 * jq + 0] - Q[i]; v4.y = P[i][4 * jq + 1] - Q[i];
        v4.z = P[i][4 * jq + 2] - Q[i]; v4.w = P[i][4 * jq + 3] - Q[i];
        *(float4*)&red[slot * 4096 + (4 * p + i) * 256 + g * 16 + jq * 4] = v4;
      }
    }
  }
  if (g == 0) {
#pragma unroll
    for (int i = 0; i < 4; i++) redS[wave * 16 + 4 * p + i] = Sa[i];
  }
  __syncthreads();
  if (wave >= 4) {
#pragma unroll
    for (int i = 0; i < 4; i++) {
#pragma unroll
      for (int jq = 0; jq < 4; jq++) {
        float4* dst = (float4*)&red[slot * 4096 + (4 * p + i) * 256 + g * 16 + jq * 4];
        float4 c = *dst;
        c.x += P[i][4 * jq + 0] - Q[i]; c.y += P[i][4 * jq + 1] - Q[i];
        c.z += P[i][4 * jq + 2] - Q[i]; c.w += P[i][4 * jq + 3] - Q[i];
        *dst = c;
      }
    }
  }
  __syncthreads();
#pragma unroll
  for (int k = 0; k < 8; k++) {
    int idx = k * 512 + t;
    float v = red[idx] + red[4096 + idx] + red[8192 + idx] + red[12288 + idx];
    ws[WS_PARTU + (size_t)blockIdx.x * 4096 + idx] = v;
  }
  if (t < 16) {
    float sv = 0.f;
#pragma unroll
    for (int w = 0; w < 8; w++) sv += redS[w * 16 + t];
    ws[WS_PARTS + blockIdx.x * 16 + t] = sv;
  }
}

// =====================================================================
// K_slot: fused slot-side chain for one iteration, 128 blocks x 256 thr.
// phase0 red -> bar -> phase1 gxgh -> bar -> phase2 midh1 -> bar ->
// phase3 ffnew -> bar -> phase4 qkg (skipped on last iter).
// =====================================================================
__global__ __launch_bounds__(256) void k_slot(
    const float* __restrict__ W_hh, const float* __restrict__ b_hh,
    const float* __restrict__ g_in, const float* __restrict__ be_in,
    const float* __restrict__ W1, const float* __restrict__ b1,
    const float* __restrict__ g_f, const float* __restrict__ be_f,
    const float* __restrict__ W2, const float* __restrict__ b2v,
    const float* __restrict__ g_s, const float* __restrict__ be_s,
    float* __restrict__ out, float* __restrict__ ws, int it)
{
  __shared__ __align__(16) float smem[4704];  // 18.4 KB, aliased per phase
  float* sBuf  = smem;            // 16*260
  float* sAux  = smem + 4160;     // 512
  float* sStat = smem + 4672;     // 32
  int bid = blockIdx.x, t = threadIdx.x;
  unsigned int* ctr = (unsigned int*)(ws + WS_CTR);
  unsigned int base = (unsigned int)it * 4u * SLOT_BLOCKS;

  // ---- phase 0: reduce 512 partial slices -> U[16][256], S[16] ----
  {
    int le = t & 31, grp = t >> 5;                 // 8 groups of 32
    int e = bid * 32 + le;
    float acc = 0.f;
#pragma unroll 8
    for (int k = 0; k < 64; k++)
      acc += ws[WS_PARTU + (size_t)(grp + k * 8) * 4096 + e];
    sAux[t] = acc;
    __syncthreads();
    if (t < 32) {
      float s = 0.f;
#pragma unroll
      for (int w = 0; w < 8; w++) s += sAux[w * 32 + t];
      ws[WS_U + bid * 32 + t] = s;
    }
    if (bid == 0) {
      int n = t & 15, g16 = t >> 4;                // 16 groups of 16
      float a2 = 0.f;
#pragma unroll 8
      for (int k = 0; k < 32; k++)
        a2 += ws[WS_PARTS + (g16 + k * 16) * 16 + n];
      __syncthreads();
      sAux[t] = a2;
      __syncthreads();
      if (t < 16) {
        float s = 0.f;
#pragma unroll
        for (int w = 0; w < 16; w++) s += sAux[w * 16 + t];
        ws[WS_S + t] = s;
      }
    }
  }
  gridbar(ctr, base + SLOT_BLOCKS);

  // ---- phase 1: gx (bid<64) / gh (bid>=64) ----
  {
    bool isgx = bid < 64;
    float* sU = sBuf;
    float* sInv = sStat;
    if (isgx && t < 16) sInv[t] = 1.0f / ws[WS_S + t];
    __syncthreads();
    if (isgx) {
      float gi = g_in[t], bi = be_in[t];
      for (int n = 0; n < 16; n++)
        sU[n * 260 + t] = fmaf(gi * ws[WS_U + n * 256 + t], sInv[n], bi);
    } else {
      for (int n = 0; n < 16; n++)
        sU[n * 260 + t] = ws[WS_SLOTS + n * 256 + t];
    }
    __syncthreads();
    int jr = t >> 4, n = t & 15;
    if (jr < 12) {
      int j = (isgx ? bid : bid - 64) * 12 + jr;
      const float* srow = &sU[n * 260];
      const float* wrow = isgx ? (ws + WS_WIHV + j * 256) : (W_hh + j * 256);
      float acc = isgx ? ws[WS_BGX + j] : b_hh[j];
#pragma unroll 8
      for (int k = 0; k < 64; k++) {
        float4 w = *(const float4*)(wrow + k * 4);
        float4 s4 = *(const float4*)(srow + k * 4);
        acc = fmaf(w.x, s4.x, fmaf(w.y, s4.y, fmaf(w.z, s4.z, fmaf(w.w, s4.w, acc))));
      }
      if (isgx) ws[WS_GX + n * 768 + j] = acc;
      else      ws[WS_GH + n * 768 + j] = acc;
    }
  }
  gridbar(ctr, base + 2 * SLOT_BLOCKS);

  // ---- phase 2: GRU gates -> mid; LN(g_f); h1 = relu(lnf@W1.T+b1) ----
  if (bid < 64) {
    float* sM = sBuf;
    for (int n = 0; n < 16; n++) {
      float xr = ws[WS_GX + n * 768 + t],       hr = ws[WS_GH + n * 768 + t];
      float xz = ws[WS_GX + n * 768 + 256 + t], hz = ws[WS_GH + n * 768 + 256 + t];
      float xn = ws[WS_GX + n * 768 + 512 + t], hn = ws[WS_GH + n * 768 + 512 + t];
      float sp = ws[WS_SLOTS + n * 256 + t];
      float r = 1.f / (1.f + __expf(-(xr + hr)));
      float z = 1.f / (1.f + __expf(-(xz + hz)));
      float nn = tanhf(fmaf(r, hn, xn));
      float mid = fmaf(z, sp - nn, nn);
      sM[n * 260 + t] = mid;
      if (bid == 0) ws[WS_MID + n * 256 + t] = mid;
    }
    __syncthreads();
    { int n = t >> 4, c = t & 15;
      float s1 = 0.f, s2 = 0.f;
      for (int k = 0; k < 16; k++) {
        float x = sM[n * 260 + c * 16 + k];
        s1 += x; s2 = fmaf(x, x, s2);
      }
      sAux[n * 16 + c] = s1; sAux[256 + n * 16 + c] = s2; }
    __syncthreads();
    if (t < 16) {
      float s1 = 0.f, s2 = 0.f;
      for (int c = 0; c < 16; c++) { s1 += sAux[t * 16 + c]; s2 += sAux[256 + t * 16 + c]; }
      float m = s1 * (1.f / 256.f);
      float v = fmaxf(fmaf(-m, m, s2 * (1.f / 256.f)), 0.f);
      sStat[t] = m; sStat[16 + t] = rsqrtf(v + LN_EPS);
    }
    __syncthreads();
    { float gf = g_f[t], bf = be_f[t];
      for (int n = 0; n < 16; n++) {
        float m = sStat[n], rs = sStat[16 + n];
        sM[n * 260 + t] = fmaf((sM[n * 260 + t] - m) * rs, gf, bf);
      } }
    __syncthreads();
    int jr = t >> 6, n = (t >> 2) & 15, ks = t & 3;
    int j = bid * 4 + jr;
    const float* wrow = W1 + j * 256 + ks * 64;
    const float* srow = &sM[n * 260 + ks * 64];
    float acc = 0.f;
#pragma unroll
    for (int k = 0; k < 16; k++) {
      float4 w = *(const float4*)(wrow + k * 4);
      float4 s4 = *(const float4*)(srow + k * 4);
      acc = fmaf(w.x, s4.x, fmaf(w.y, s4.y, fmaf(w.z, s4.z, fmaf(w.w, s4.w, acc))));
    }
    sAux[t] = acc;
    __syncthreads();
    if (t < 64) {
      int jr2 = t >> 4, n2 = t & 15;
      int j2 = bid * 4 + jr2;
      int b = jr2 * 64 + n2 * 4;
      float s = sAux[b] + sAux[b + 1] + sAux[b + 2] + sAux[b + 3] + b1[j2];
      ws[WS_H1 + n2 * 256 + j2] = fmaxf(s, 0.f);
    }
  }
  gridbar(ctr, base + 3 * SLOT_BLOCKS);

  // ---- phase 3: ff = h1@W2.T + b2; slots = mid + ff -> ws.slots, out ----
  if (bid < 64) {
    float* sH = sBuf;
    for (int n = 0; n < 16; n++)
      sH[n * 260 + t] = ws[WS_H1 + n * 256 + t];
    __syncthreads();
    int dr = t >> 6, n = (t >> 2) & 15, ks = t & 3;
    int d = bid * 4 + dr;
    const float* wrow = W2 + d * 256 + ks * 64;
    const float* srow = &sH[n * 260 + ks * 64];
    float acc = 0.f;
#pragma unroll
    for (int k = 0; k < 16; k++) {
      float4 w = *(const float4*)(wrow + k * 4);
      float4 s4 = *(const float4*)(srow + k * 4);
      acc = fmaf(w.x, s4.x, fmaf(w.y, s4.y, fmaf(w.z, s4.z, fmaf(w.w, s4.w, acc))));
    }
    sAux[t] = acc;
    __syncthreads();
    if (t < 64) {
      int dr2 = t >> 4, n2 = t & 15;
      int d2 = bid * 4 + dr2;
      int b = dr2 * 64 + n2 * 4;
      float s = sAux[b] + sAux[b + 1] + sAux[b + 2] + sAux[b + 3]
              + b2v[d2] + ws[WS_MID + n2 * 256 + d2];
      ws[WS_SLOTS + n2 * 256 + d2] = s;
      out[n2 * 256 + d2] = s;
    }
  }
  gridbar(ctr, base + 4 * SLOT_BLOCKS);

  // ---- phase 4: qkg/qb for next iteration (skip on last iter) ----
  if (it < 2 && bid <= 64) {
    float* sS = sBuf;
    for (int n = 0; n < 16; n++)
      sS[n * 260 + t] = ws[WS_SLOTS + n * 256 + t];
    __syncthreads();
    { int n = t >> 4, c = t & 15;
      float s1 = 0.f, s2 = 0.f;
      for (int k = 0; k < 16; k++) {
        float x = sS[n * 260 + c * 16 + k];
        s1 += x; s2 = fmaf(x, x, s2);
      }
      sAux[n * 16 + c] = s1; sAux[256 + n * 16 + c] = s2; }
    __syncthreads();
    if (t < 16) {
      float s1 = 0.f, s2 = 0.f;
      for (int c = 0; c < 16; c++) { s1 += sAux[t * 16 + c]; s2 += sAux[256 + t * 16 + c]; }
      float m = s1 * (1.f / 256.f);
      float v = fmaxf(fmaf(-m, m, s2 * (1.f / 256.f)), 0.f);
      sStat[t] = m; sStat[16 + t] = rsqrtf(v + LN_EPS);
    }
    __syncthreads();
    { float gs = g_s[t], bs = be_s[t];
      for (int n = 0; n < 16; n++) {
        float m = sStat[n], rs = sStat[16 + n];
        sS[n * 260 + t] = fmaf((sS[n * 260 + t] - m) * rs, gs, bs);
      } }
    __syncthreads();
    if (bid < 64) {
      int cr = t >> 6, n = (t >> 2) & 15, ks = t & 3;
      int c = bid * 4 + cr;
      const float* wrow = ws + WS_WQKG + c * 256 + ks * 64;
      const float* srow = &sS[n * 260 + ks * 64];
      float acc = 0.f;
#pragma unroll
      for (int i = 0; i < 16; i++) {
        float4 w = *(const float4*)(wrow + i * 4);
        float4 s4 = *(const float4*)(srow + i * 4);
        acc = fmaf(w.x, s4.x, fmaf(w.y, s4.y, fmaf(w.z, s4.z, fmaf(w.w, s4.w, acc))));
      }
      sAux[t] = acc;
      __syncthreads();
      if (t < 64) {
        int cr2 = t >> 4, n2 = t & 15;
        int c2 = bid * 4 + cr2;
        int b = cr2 * 64 + n2 * 4;
        float s = sAux[b] + sAux[b + 1] + sAux[b + 2] + sAux[b + 3];
        ws[WS_QKG + n2 * 256 + c2] = s + ws[WS_U2G + c2];
      }
    } else {
      int n = t >> 4, ks = t & 15;
      float acc = 0.f;
      for (int k = 0; k < 16; k++)
        acc = fmaf(sS[n * 260 + ks * 16 + k], ws[WS_U1 + ks * 16 + k], acc);
      sAux[t] = acc;
      __syncthreads();
      if (t < 16) {
        float s = 0.f;
        for (int k = 0; k < 16; k++) s += sAux[t * 16 + k];
        ws[WS_QB + t] = SCALE * (s + ws[WS_C1]);
      }
    }
  }
}

// =====================================================================
extern "C" void kernel_launch(void* const* d_in, const int* in_sizes, int n_in,
                              void* d_out, int out_size, void* d_ws, size_t ws_size,
                              hipStream_t stream)
{
  (void)in_sizes; (void)n_in; (void)out_size; (void)ws_size;
  const float* inputs = (const float*)d_in[0];
  const float* noise  = (const float*)d_in[1];
  const float* mu     = (const float*)d_in[2];
  const float* sigma  = (const float*)d_in[3];
  const float* Wq     = (const float*)d_in[4];
  const float* bq     = (const float*)d_in[5];
  const float* Wk     = (const float*)d_in[6];
  const float* bk     = (const float*)d_in[7];
  const float* Wv     = (const float*)d_in[8];
  const float* bv     = (const float*)d_in[9];
  const float* W_ih   = (const float*)d_in[10];
  const float* W_hh   = (const float*)d_in[11];
  const float* b_ih   = (const float*)d_in[12];
  const float* b_hh   = (const float*)d_in[13];
  const float* W1     = (const float*)d_in[14];
  const float* b1     = (const float*)d_in[15];
  const float* W2     = (const float*)d_in[16];
  const float* b2     = (const float*)d_in[17];
  const float* g_in   = (const float*)d_in[18];
  const float* be_in  = (const float*)d_in[19];
  const float* g_s    = (const float*)d_in[20];
  const float* be_s   = (const float*)d_in[21];
  const float* g_f    = (const float*)d_in[22];
  const float* be_f   = (const float*)d_in[23];
  float* ws = (float*)d_ws;
  float* out = (float*)d_out;

  hipLaunchKernelGGL(k_pre1, dim3(81), dim3(256), 0, stream,
                     Wq, bq, Wk, bk, Wv, bv, W_ih, b_ih, g_in, be_in, ws);
  hipLaunchKernelGGL(k_qkg, dim3(65), dim3(256), 0, stream,
                     noise, mu, sigma, g_s, be_s, ws, 1);
  for (int it = 0; it < 3; it++) {
    hipLaunchKernelGGL(k_big, dim3(BIG_BLOCKS), dim3(BIG_THREADS), 0, stream, inputs, ws);
    hipLaunchKernelGGL(k_slot, dim3(SLOT_BLOCKS), dim3(256), 0, stream,
                       W_hh, b_hh, g_in, be_in, W1, b1, g_f, be_f,
                       W2, b2, g_s, be_s, out, ws, it);
  }
}

// Round 3
// 634.558 us; speedup vs baseline: 2.1321x; 1.1798x over previous
//
#include <hip/hip_runtime.h>
#include <stdint.h>

#define B_ROWS 131072
#define SCALE 0.0625f
#define LN_EPS 1e-5f
#define ATTN_EPS 1e-8f

#define BIG_BLOCKS 512
#define BIG_THREADS 512
#define ROWS_PER_BLOCK (B_ROWS / BIG_BLOCKS)   // 256
#define ROWS_PER_WAVE  (ROWS_PER_BLOCK / 8)    // 32 (8 waves/block)
#define NSLICE BIG_BLOCKS                      // 512 partial slices

// ---- workspace layout (float offsets) ----
#define WS_PARTU 0
#define WS_PARTS (WS_PARTU + NSLICE*4096)        // 2097152
#define WS_U     (WS_PARTS + NSLICE*16)          // 2105344
#define WS_S     (WS_U + 4096)                   // 2109440
#define WS_SLOTS (WS_S + 64)                     // 2109504
#define WS_MID   (WS_SLOTS + 4096)               // 2113600
#define WS_GX    (WS_MID + 4096)                 // 2117696
#define WS_GH    (WS_GX + 12288)                 // 2129984
#define WS_H1    (WS_GH + 12288)                 // 2142272
#define WS_QKG   (WS_H1 + 4096)                  // 2146368
#define WS_QB    (WS_QKG + 4096)                 // 2150464
#define WS_WIHV  (WS_QB + 64)                    // 2150528
#define WS_BGX   (WS_WIHV + 196608)              // 2347136
#define WS_WQKG  (WS_BGX + 768)                  // 2347904
#define WS_U2G   (WS_WQKG + 65536)               // 2413440
#define WS_U1    (WS_U2G + 256)                  // 2413696
#define WS_C1    (WS_U1 + 256)                   // 2413952
// total ~2413953 floats ~ 9.66 MB

// =====================================================================
// K_pre1: weight compositions (fp32 inputs)
// =====================================================================
__global__ __launch_bounds__(256) void k_pre1(
    const float* __restrict__ Wq, const float* __restrict__ bq,
    const float* __restrict__ Wk, const float* __restrict__ bk,
    const float* __restrict__ Wv, const float* __restrict__ bv,
    const float* __restrict__ W_ih, const float* __restrict__ b_ih,
    const float* __restrict__ g_in, const float* __restrict__ be_in,
    float* __restrict__ ws)
{
  int bid = blockIdx.x, t = threadIdx.x;
  if (bid < 48) {
    int j0 = bid * 16;
    float acc[16];
#pragma unroll
    for (int r = 0; r < 16; r++) acc[r] = 0.f;
    int d = t;
    for (int dd = 0; dd < 256; dd++) {
      float v = Wv[dd * 256 + d];
#pragma unroll
      for (int r = 0; r < 16; r++)
        acc[r] = fmaf(W_ih[(j0 + r) * 256 + dd], v, acc[r]);
    }
#pragma unroll
    for (int r = 0; r < 16; r++) ws[WS_WIHV + (j0 + r) * 256 + d] = acc[r];
    if (t < 16) {
      int j = j0 + t;
      float a = b_ih[j];
      for (int dd = 0; dd < 256; dd++)
        a = fmaf(W_ih[j * 256 + dd], bv[dd], a);
      ws[WS_BGX + j] = a;
    }
  } else if (bid < 80) {
    int c0 = (bid - 48) * 8;
    float acc[8];
#pragma unroll
    for (int r = 0; r < 8; r++) acc[r] = 0.f;
    int d = t;
    for (int i = 0; i < 256; i++) {
      float wq = Wq[i * 256 + d];
#pragma unroll
      for (int r = 0; r < 8; r++)
        acc[r] = fmaf(wq, Wk[i * 256 + c0 + r], acc[r]);
    }
#pragma unroll
    for (int r = 0; r < 8; r++) {
      float gc = g_in[c0 + r];
      ws[WS_WQKG + (c0 + r) * 256 + d] = SCALE * gc * acc[r];
    }
    if (t < 8) {
      int c = c0 + t;
      float a = 0.f;
      for (int i = 0; i < 256; i++)
        a = fmaf(bq[i], Wk[i * 256 + c], a);
      ws[WS_U2G + c] = SCALE * g_in[c] * a;
    }
  } else {
    __shared__ __align__(16) float t2[256];
    int j = t;
    float a = 0.f;
    for (int dp = 0; dp < 256; dp++)
      a = fmaf(Wk[j * 256 + dp], be_in[dp], a);
    t2[j] = a + bk[j];
    __syncthreads();
    int d = t;
    float u = 0.f;
    for (int i = 0; i < 256; i++)
      u = fmaf(Wq[i * 256 + d], t2[i], u);
    ws[WS_U1 + d] = u;
    if (t == 0) {
      float c = 0.f;
      for (int i = 0; i < 256; i++) c = fmaf(bq[i], t2[i], c);
      ws[WS_C1] = c;
    }
  }
}

// =====================================================================
// K_qkg: s = LN(slots, g_s, be_s);  qkg[n][c] = s[n]·WqkgT[c] + u2g[c]
//        qb[n] = SCALE*(s[n]·u1 + c1).  init: slots = mu + sigma*noise.
// =====================================================================
__global__ __launch_bounds__(256) void k_qkg(
    const float* __restrict__ noise, const float* __restrict__ mu,
    const float* __restrict__ sigma, const float* __restrict__ g_s,
    const float* __restrict__ be_s, float* __restrict__ ws, int init)
{
  __shared__ __align__(16) float sS[16 * 260];
  __shared__ __align__(16) float sAux[512];
  __shared__ __align__(16) float sStat[32];
  int bid = blockIdx.x, t = threadIdx.x;
  for (int n = 0; n < 16; n++) {
    float v;
    if (init) v = fmaf(sigma[t], noise[n * 256 + t], mu[t]);
    else      v = ws[WS_SLOTS + n * 256 + t];
    sS[n * 260 + t] = v;
    if (init && bid == 0) ws[WS_SLOTS + n * 256 + t] = v;
  }
  __syncthreads();
  { int n = t >> 4, c = t & 15;
    float s1 = 0.f, s2 = 0.f;
    for (int k = 0; k < 16; k++) {
      float x = sS[n * 260 + c * 16 + k];
      s1 += x; s2 = fmaf(x, x, s2);
    }
    sAux[n * 16 + c] = s1; sAux[256 + n * 16 + c] = s2; }
  __syncthreads();
  if (t < 16) {
    float s1 = 0.f, s2 = 0.f;
    for (int c = 0; c < 16; c++) { s1 += sAux[t * 16 + c]; s2 += sAux[256 + t * 16 + c]; }
    float m = s1 * (1.f / 256.f);
    float v = fmaxf(fmaf(-m, m, s2 * (1.f / 256.f)), 0.f);
    sStat[t] = m; sStat[16 + t] = rsqrtf(v + LN_EPS);
  }
  __syncthreads();
  { float gs = g_s[t], bs = be_s[t];
    for (int n = 0; n < 16; n++) {
      float m = sStat[n], rs = sStat[16 + n];
      sS[n * 260 + t] = fmaf((sS[n * 260 + t] - m) * rs, gs, bs);
    } }
  __syncthreads();
  if (bid < 64) {
    int cr = t >> 6, n = (t >> 2) & 15, ks = t & 3;
    int c = bid * 4 + cr;
    const float* wrow = ws + WS_WQKG + c * 256 + ks * 64;
    const float* srow = &sS[n * 260 + ks * 64];
    float acc = 0.f;
#pragma unroll
    for (int i = 0; i < 16; i++) {
      float4 w = *(const float4*)(wrow + i * 4);
      float4 s4 = *(const float4*)(srow + i * 4);
      acc = fmaf(w.x, s4.x, fmaf(w.y, s4.y, fmaf(w.z, s4.z, fmaf(w.w, s4.w, acc))));
    }
    sAux[t] = acc;
    __syncthreads();
    if (t < 64) {
      int cr2 = t >> 4, n2 = t & 15;
      int c2 = bid * 4 + cr2;
      int b = cr2 * 64 + n2 * 4;
      float s = sAux[b] + sAux[b + 1] + sAux[b + 2] + sAux[b + 3];
      ws[WS_QKG + n2 * 256 + c2] = s + ws[WS_U2G + c2];
    }
  } else {
    int n = t >> 4, ks = t & 15;
    float acc = 0.f;
    for (int k = 0; k < 16; k++)
      acc = fmaf(sS[n * 260 + ks * 16 + k], ws[WS_U1 + ks * 16 + k], acc);
    sAux[t] = acc;
    __syncthreads();
    if (t < 16) {
      float s = 0.f;
      for (int k = 0; k < 16; k++) s += sAux[t * 16 + k];
      ws[WS_QB + t] = SCALE * (s + ws[WS_C1]);
    }
  }
}

// =====================================================================
// K_big: 512 threads, 8 waves, 32 rows/wave, processed as 16 row-PAIRS.
// Two independent dependency chains per wave (4 per SIMD) hide the
// serial shuffle-reduce latency that capped VALUBusy at 43%.
// P/qw are shared across the pair (accumulators), so reg growth is
// only +32 (second x + pair prefetch): ~240 total, inside (512,2)'s
// 256 budget. (512,4) = 64-reg cap caused scratch spills. Occupancy
// stays 2 waves/SIMD (V+A total > 128); that is structural.
// =====================================================================
__global__ __launch_bounds__(512, 2) void k_big(
    const float* __restrict__ X, float* __restrict__ ws)
{
  __shared__ __align__(16) float red[4 * 4096];   // 64 KB
  __shared__ __align__(16) float redS[128];       // 8 waves x 16
  int t = threadIdx.x;
  int wave = t >> 6, lane = t & 63;
  int p = lane >> 4, g = lane & 15;

  const float* qkg = ws + WS_QKG;
  float qw[4][16];
  float qs[4];
#pragma unroll
  for (int i = 0; i < 4; i++) {
    const float* rp = qkg + (4 * p + i) * 256 + g * 16;
#pragma unroll
    for (int jq = 0; jq < 4; jq++) {
      float4 v4 = *(const float4*)(rp + 4 * jq);
      qw[i][4 * jq + 0] = v4.x; qw[i][4 * jq + 1] = v4.y;
      qw[i][4 * jq + 2] = v4.z; qw[i][4 * jq + 3] = v4.w;
    }
    float s = 0.f;
#pragma unroll
    for (int j = 0; j < 16; j++) s += qw[i][j];
    qs[i] = s;
  }
#pragma unroll
  for (int m = 1; m <= 8; m <<= 1) {
#pragma unroll
    for (int i = 0; i < 4; i++) qs[i] += __shfl_xor(qs[i], m);
  }
  float qb0[4];
  {
    float4 q4 = *(const float4*)(ws + WS_QB + 4 * p);
    qb0[0] = q4.x; qb0[1] = q4.y; qb0[2] = q4.z; qb0[3] = q4.w;
  }

  float P[4][16];
#pragma unroll
  for (int i = 0; i < 4; i++)
#pragma unroll
    for (int j = 0; j < 16; j++) P[i][j] = 0.f;
  float Q[4] = {0.f, 0.f, 0.f, 0.f};
  float Sa[4] = {0.f, 0.f, 0.f, 0.f};

  size_t rowbase = (size_t)blockIdx.x * ROWS_PER_BLOCK + (size_t)wave * ROWS_PER_WAVE;
  const float* base = X + rowbase * 256 + g * 16;

  float4 cA0 = *(const float4*)(base + 0);
  float4 cB0 = *(const float4*)(base + 4);
  float4 cC0 = *(const float4*)(base + 8);
  float4 cD0 = *(const float4*)(base + 12);
  float4 cA1 = *(const float4*)(base + 256);
  float4 cB1 = *(const float4*)(base + 260);
  float4 cC1 = *(const float4*)(base + 264);
  float4 cD1 = *(const float4*)(base + 268);

#pragma unroll 1
  for (int r = 0; r < ROWS_PER_WAVE; r += 2) {
    const float* nx = base + (size_t)((r + 2 < ROWS_PER_WAVE) ? (r + 2) : 0) * 256;
    float4 pA0 = *(const float4*)(nx + 0);
    float4 pB0 = *(const float4*)(nx + 4);
    float4 pC0 = *(const float4*)(nx + 8);
    float4 pD0 = *(const float4*)(nx + 12);
    float4 pA1 = *(const float4*)(nx + 256);
    float4 pB1 = *(const float4*)(nx + 260);
    float4 pC1 = *(const float4*)(nx + 264);
    float4 pD1 = *(const float4*)(nx + 268);

    float x0[16], x1[16];
    x0[0] = cA0.x; x0[1] = cA0.y; x0[2] = cA0.z; x0[3] = cA0.w;
    x0[4] = cB0.x; x0[5] = cB0.y; x0[6] = cB0.z; x0[7] = cB0.w;
    x0[8] = cC0.x; x0[9] = cC0.y; x0[10] = cC0.z; x0[11] = cC0.w;
    x0[12] = cD0.x; x0[13] = cD0.y; x0[14] = cD0.z; x0[15] = cD0.w;
    x1[0] = cA1.x; x1[1] = cA1.y; x1[2] = cA1.z; x1[3] = cA1.w;
    x1[4] = cB1.x; x1[5] = cB1.y; x1[6] = cB1.z; x1[7] = cB1.w;
    x1[8] = cC1.x; x1[9] = cC1.y; x1[10] = cC1.z; x1[11] = cC1.w;
    x1[12] = cD1.x; x1[13] = cD1.y; x1[14] = cD1.z; x1[15] = cD1.w;

    // ---- stats, both rows interleaved ----
    float s10 = 0.f, s20 = 0.f, s11 = 0.f, s21 = 0.f;
#pragma unroll
    for (int j = 0; j < 16; j++) {
      s10 += x0[j]; s20 = fmaf(x0[j], x0[j], s20);
      s11 += x1[j]; s21 = fmaf(x1[j], x1[j], s21);
    }
#pragma unroll
    for (int m = 1; m <= 8; m <<= 1) {
      s10 += __shfl_xor(s10, m); s11 += __shfl_xor(s11, m);
      s20 += __shfl_xor(s20, m); s21 += __shfl_xor(s21, m);
    }
    float mean0 = s10 * (1.f / 256.f), mean1 = s11 * (1.f / 256.f);
    float var0 = fmaxf(fmaf(-mean0, mean0, s20 * (1.f / 256.f)), 0.f);
    float var1 = fmaxf(fmaf(-mean1, mean1, s21 * (1.f / 256.f)), 0.f);
    float rs0 = rsqrtf(var0 + LN_EPS), rs1 = rsqrtf(var1 + LN_EPS);
    float mrs0 = mean0 * rs0, mrs1 = mean1 * rs1;

    // ---- dots, both rows interleaved ----
    float d0[4] = {0.f, 0.f, 0.f, 0.f};
    float d1[4] = {0.f, 0.f, 0.f, 0.f};
#pragma unroll
    for (int j = 0; j < 16; j++) {
#pragma unroll
      for (int i = 0; i < 4; i++) {
        d0[i] = fmaf(qw[i][j], x0[j], d0[i]);
        d1[i] = fmaf(qw[i][j], x1[j], d1[i]);
      }
    }
#pragma unroll
    for (int m = 1; m <= 8; m <<= 1) {
#pragma unroll
      for (int i = 0; i < 4; i++) {
        d0[i] += __shfl_xor(d0[i], m);
        d1[i] += __shfl_xor(d1[i], m);
      }
    }
    float dsc0[4], dsc1[4];
#pragma unroll
    for (int i = 0; i < 4; i++) {
      dsc0[i] = fmaf(rs0, d0[i], fmaf(-mrs0, qs[i], qb0[i]));
      dsc1[i] = fmaf(rs1, d1[i], fmaf(-mrs1, qs[i], qb0[i]));
    }

    // ---- softmax, both rows interleaved ----
    float mx0 = fmaxf(fmaxf(dsc0[0], dsc0[1]), fmaxf(dsc0[2], dsc0[3]));
    float mx1 = fmaxf(fmaxf(dsc1[0], dsc1[1]), fmaxf(dsc1[2], dsc1[3]));
    mx0 = fmaxf(mx0, __shfl_xor(mx0, 16)); mx1 = fmaxf(mx1, __shfl_xor(mx1, 16));
    mx0 = fmaxf(mx0, __shfl_xor(mx0, 32)); mx1 = fmaxf(mx1, __shfl_xor(mx1, 32));
    float e0[4], e1[4];
#pragma unroll
    for (int i = 0; i < 4; i++) {
      e0[i] = __expf(dsc0[i] - mx0);
      e1[i] = __expf(dsc1[i] - mx1);
    }
    float se0 = e0[0] + e0[1] + e0[2] + e0[3];
    float se1 = e1[0] + e1[1] + e1[2] + e1[3];
    se0 += __shfl_xor(se0, 16); se1 += __shfl_xor(se1, 16);
    se0 += __shfl_xor(se0, 32); se1 += __shfl_xor(se1, 32);
    float inv0 = 1.0f / se0, inv1 = 1.0f / se1;
    float a0v[4], ar0[4], a1v[4], ar1[4];
#pragma unroll
    for (int i = 0; i < 4; i++) {
      a0v[i] = fmaf(e0[i], inv0, ATTN_EPS); ar0[i] = a0v[i] * rs0;
      a1v[i] = fmaf(e1[i], inv1, ATTN_EPS); ar1[i] = a1v[i] * rs1;
    }

    // ---- P accumulation (shared accumulators, row r then r+1) ----
#pragma unroll
    for (int j = 0; j < 16; j++) {
#pragma unroll
      for (int i = 0; i < 4; i++) {
        P[i][j] = fmaf(ar0[i], x0[j], P[i][j]);
        P[i][j] = fmaf(ar1[i], x1[j], P[i][j]);
      }
    }
#pragma unroll
    for (int i = 0; i < 4; i++) {
      Q[i] = fmaf(a0v[i], mrs0, Q[i]);
      Q[i] = fmaf(a1v[i], mrs1, Q[i]);
      Sa[i] += a0v[i];
      Sa[i] += a1v[i];
    }

    cA0 = pA0; cB0 = pB0; cC0 = pC0; cD0 = pD0;
    cA1 = pA1; cB1 = pB1; cC1 = pC1; cD1 = pD1;
  }

  // Two-stage cross-wave reduce in 64KB LDS (Uy = P - Q per slot/elem).
  int slot = wave & 3;
  if (wave < 4) {
#pragma unroll
    for (int i = 0; i < 4; i++) {
#pragma unroll
      for (int jq = 0; jq < 4; jq++) {
        float4 v4;
        v4.x = P[i][4 * jq + 0] - Q[i]; v4.y = P[i][4 * jq + 1] - Q[i];
        v4.z = P[i][4 * jq + 2] - Q[i]; v4.w = P[i][4 * jq + 3] - Q[i];
        *(float4*)&red[slot * 4096 + (4 * p + i) * 256 + g * 16 + jq * 4] = v4;
      }
    }
  }
  if (g == 0) {
#pragma unroll
    for (int i = 0; i < 4; i++) redS[wave * 16 + 4 * p + i] = Sa[i];
  }
  __syncthreads();
  if (wave >= 4) {
#pragma unroll
    for (int i = 0; i < 4; i++) {
#pragma unroll
      for (int jq = 0; jq < 4; jq++) {
        float4* dst = (float4*)&red[slot * 4096 + (4 * p + i) * 256 + g * 16 + jq * 4];
        float4 c = *dst;
        c.x += P[i][4 * jq + 0] - Q[i]; c.y += P[i][4 * jq + 1] - Q[i];
        c.z += P[i][4 * jq + 2] - Q[i]; c.w += P[i][4 * jq + 3] - Q[i];
        *dst = c;
      }
    }
  }
  __syncthreads();
#pragma unroll
  for (int k = 0; k < 8; k++) {
    int idx = k * 512 + t;
    float v = red[idx] + red[4096 + idx] + red[8192 + idx] + red[12288 + idx];
    ws[WS_PARTU + (size_t)blockIdx.x * 4096 + idx] = v;
  }
  if (t < 16) {
    float sv = 0.f;
#pragma unroll
    for (int w = 0; w < 8; w++) sv += redS[w * 16 + t];
    ws[WS_PARTS + blockIdx.x * 16 + t] = sv;
  }
}

// =====================================================================
// K_red: reduce 512 partial slices -> U[16][256], S[16]
// =====================================================================
__global__ __launch_bounds__(256) void k_red(float* __restrict__ ws)
{
  __shared__ __align__(16) float sAux[256];
  int bid = blockIdx.x, t = threadIdx.x;
  if (bid < 256) {
    int el = t & 15, wg = t >> 4;
    int e = bid * 16 + el;
    float acc = 0.f;
#pragma unroll 8
    for (int k = 0; k < 32; k++)
      acc += ws[WS_PARTU + (size_t)(wg + k * 16) * 4096 + e];
    sAux[t] = acc;
    __syncthreads();
    if (t < 16) {
      float s = 0.f;
      for (int w = 0; w < 16; w++) s += sAux[w * 16 + t];
      ws[WS_U + bid * 16 + t] = s;
    }
  } else {
    int n = t & 15, wg = t >> 4;
    float acc = 0.f;
#pragma unroll 8
    for (int k = 0; k < 32; k++)
      acc += ws[WS_PARTS + (wg + k * 16) * 16 + n];
    sAux[t] = acc;
    __syncthreads();
    if (t < 16) {
      float s = 0.f;
      for (int w = 0; w < 16; w++) s += sAux[w * 16 + t];
      ws[WS_S + t] = s;
    }
  }
}

// =====================================================================
// K_gxgh: bid<64:  gx[n][j] = W_ihv[j]·(g_in*(U[n]/S[n]) + be_in) + bgx[j]
//         bid>=64: gh[n][j] = W_hh[j]·slots_prev[n] + b_hh[j]
// =====================================================================
__global__ __launch_bounds__(256) void k_gxgh(
    const float* __restrict__ W_hh, const float* __restrict__ b_hh,
    const float* __restrict__ g_in, const float* __restrict__ be_in,
    float* __restrict__ ws)
{
  __shared__ __align__(16) float sU[16 * 260];
  __shared__ __align__(16) float sInv[16];
  int bid = blockIdx.x, t = threadIdx.x;
  bool isgx = bid < 64;
  if (isgx && t < 16) sInv[t] = 1.0f / ws[WS_S + t];
  __syncthreads();
  if (isgx) {
    float gi = g_in[t], bi = be_in[t];
    for (int n = 0; n < 16; n++)
      sU[n * 260 + t] = fmaf(gi * ws[WS_U + n * 256 + t], sInv[n], bi);
  } else {
    for (int n = 0; n < 16; n++)
      sU[n * 260 + t] = ws[WS_SLOTS + n * 256 + t];
  }
  __syncthreads();
  int jr = t >> 4, n = t & 15;
  if (jr < 12) {
    int j = (isgx ? bid : bid - 64) * 12 + jr;
    const float* srow = &sU[n * 260];
    const float* wrow = isgx ? (ws + WS_WIHV + j * 256) : (W_hh + j * 256);
    float acc = isgx ? ws[WS_BGX + j] : b_hh[j];
#pragma unroll 8
    for (int k = 0; k < 64; k++) {
      float4 w = *(const float4*)(wrow + k * 4);
      float4 s4 = *(const float4*)(srow + k * 4);
      acc = fmaf(w.x, s4.x, fmaf(w.y, s4.y, fmaf(w.z, s4.z, fmaf(w.w, s4.w, acc))));
    }
    if (isgx) ws[WS_GX + n * 768 + j] = acc;
    else      ws[WS_GH + n * 768 + j] = acc;
  }
}

// =====================================================================
// K_midh1: GRU gates -> slots_mid; LN(g_f,be_f); h1 = relu(lnf@W1.T + b1)
// =====================================================================
__global__ __launch_bounds__(256) void k_midh1(
    const float* __restrict__ W1, const float* __restrict__ b1,
    const float* __restrict__ g_f, const float* __restrict__ be_f,
    float* __restrict__ ws)
{
  __shared__ __align__(16) float sM[16 * 260];
  __shared__ __align__(16) float sAux[512];
  __shared__ __align__(16) float sStat[32];
  int bid = blockIdx.x, t = threadIdx.x;
  for (int n = 0; n < 16; n++) {
    float xr = ws[WS_GX + n * 768 + t],       hr = ws[WS_GH + n * 768 + t];
    float xz = ws[WS_GX + n * 768 + 256 + t], hz = ws[WS_GH + n * 768 + 256 + t];
    float xn = ws[WS_GX + n * 768 + 512 + t], hn = ws[WS_GH + n * 768 + 512 + t];
    float sp = ws[WS_SLOTS + n * 256 + t];
    float r = 1.f / (1.f + __expf(-(xr + hr)));
    float z = 1.f / (1.f + __expf(-(xz + hz)));
    float nn = tanhf(fmaf(r, hn, xn));
    float mid = fmaf(z, sp - nn, nn);
    sM[n * 260 + t] = mid;
    if (bid == 0) ws[WS_MID + n * 256 + t] = mid;
  }
  __syncthreads();
  { int n = t >> 4, c = t & 15;
    float s1 = 0.f, s2 = 0.f;
    for (int k = 0; k < 16; k++) {
      float x = sM[n * 260 + c * 16 + k];
      s1 += x; s2 = fmaf(x, x, s2);
    }
    sAux[n * 16 + c] = s1; sAux[256 + n * 16 + c] = s2; }
  __syncthreads();
  if (t < 16) {
    float s1 = 0.f, s2 = 0.f;
    for (int c = 0; c < 16; c++) { s1 += sAux[t * 16 + c]; s2 += sAux[256 + t * 16 + c]; }
    float m = s1 * (1.f / 256.f);
    float v = fmaxf(fmaf(-m, m, s2 * (1.f / 256.f)), 0.f);
    sStat[t] = m; sStat[16 + t] = rsqrtf(v + LN_EPS);
  }
  __syncthreads();
  { float gf = g_f[t], bf = be_f[t];
    for (int n = 0; n < 16; n++) {
      float m = sStat[n], rs = sStat[16 + n];
      sM[n * 260 + t] = fmaf((sM[n * 260 + t] - m) * rs, gf, bf);
    } }
  __syncthreads();
  int jr = t >> 6, n = (t >> 2) & 15, ks = t & 3;
  int j = bid * 4 + jr;
  const float* wrow = W1 + j * 256 + ks * 64;
  const float* srow = &sM[n * 260 + ks * 64];
  float acc = 0.f;
#pragma unroll
  for (int k = 0; k < 16; k++) {
    float4 w = *(const float4*)(wrow + k * 4);
    float4 s4 = *(const float4*)(srow + k * 4);
    acc = fmaf(w.x, s4.x, fmaf(w.y, s4.y, fmaf(w.z, s4.z, fmaf(w.w, s4.w, acc))));
  }
  sAux[t] = acc;
  __syncthreads();
  if (t < 64) {
    int jr2 = t >> 4, n2 = t & 15;
    int j2 = bid * 4 + jr2;
    int b = jr2 * 64 + n2 * 4;
    float s = sAux[b] + sAux[b + 1] + sAux[b + 2] + sAux[b + 3] + b1[j2];
    ws[WS_H1 + n2 * 256 + j2] = fmaxf(s, 0.f);
  }
}

// =====================================================================
// K_ffnew: ff = h1@W2.T + b2;  slots_new = slots_mid + ff -> ws.slots, d_out
// =====================================================================
__global__ __launch_bounds__(256) void k_ffnew(
    const float* __restrict__ W2, const float* __restrict__ b2v,
    float* __restrict__ out, float* __restrict__ ws)
{
  __shared__ __align__(16) float sH[16 * 260];
  __shared__ __align__(16) float sAux[256];
  int bid = blockIdx.x, t = threadIdx.x;
  for (int n = 0; n < 16; n++)
    sH[n * 260 + t] = ws[WS_H1 + n * 256 + t];
  __syncthreads();
  int dr = t >> 6, n = (t >> 2) & 15, ks = t & 3;
  int d = bid * 4 + dr;
  const float* wrow = W2 + d * 256 + ks * 64;
  const float* srow = &sH[n * 260 + ks * 64];
  float acc = 0.f;
#pragma unroll
  for (int k = 0; k < 16; k++) {
    float4 w = *(const float4*)(wrow + k * 4);
    float4 s4 = *(const float4*)(srow + k * 4);
    acc = fmaf(w.x, s4.x, fmaf(w.y, s4.y, fmaf(w.z, s4.z, fmaf(w.w, s4.w, acc))));
  }
  sAux[t] = acc;
  __syncthreads();
  if (t < 64) {
    int dr2 = t >> 4, n2 = t & 15;
    int d2 = bid * 4 + dr2;
    int b = dr2 * 64 + n2 * 4;
    float s = sAux[b] + sAux[b + 1] + sAux[b + 2] + sAux[b + 3]
            + b2v[d2] + ws[WS_MID + n2 * 256 + d2];
    ws[WS_SLOTS + n2 * 256 + d2] = s;
    out[n2 * 256 + d2] = s;
  }
}

// =====================================================================
extern "C" void kernel_launch(void* const* d_in, const int* in_sizes, int n_in,
                              void* d_out, int out_size, void* d_ws, size_t ws_size,
                              hipStream_t stream)
{
  (void)in_sizes; (void)n_in; (void)out_size; (void)ws_size;
  const float* inputs = (const float*)d_in[0];
  const float* noise  = (const float*)d_in[1];
  const float* mu     = (const float*)d_in[2];
  const float* sigma  = (const float*)d_in[3];
  const float* Wq     = (const float*)d_in[4];
  const float* bq     = (const float*)d_in[5];
  const float* Wk     = (const float*)d_in[6];
  const float* bk     = (const float*)d_in[7];
  const float* Wv     = (const float*)d_in[8];
  const float* bv     = (const float*)d_in[9];
  const float* W_ih   = (const float*)d_in[10];
  const float* W_hh   = (const float*)d_in[11];
  const float* b_ih   = (const float*)d_in[12];
  const float* b_hh   = (const float*)d_in[13];
  const float* W1     = (const float*)d_in[14];
  const float* b1     = (const float*)d_in[15];
  const float* W2     = (const float*)d_in[16];
  const float* b2     = (const float*)d_in[17];
  const float* g_in   = (const float*)d_in[18];
  const float* be_in  = (const float*)d_in[19];
  const float* g_s    = (const float*)d_in[20];
  const float* be_s   = (const float*)d_in[21];
  const float* g_f    = (const float*)d_in[22];
  const float* be_f   = (const float*)d_in[23];
  float* ws = (float*)d_ws;
  float* out = (float*)d_out;

  hipLaunchKernelGGL(k_pre1, dim3(81), dim3(256), 0, stream,
                     Wq, bq, Wk, bk, Wv, bv, W_ih, b_ih, g_in, be_in, ws);
  hipLaunchKernelGGL(k_qkg, dim3(65), dim3(256), 0, stream,
                     noise, mu, sigma, g_s, be_s, ws, 1);
  for (int it = 0; it < 3; it++) {
    hipLaunchKernelGGL(k_big, dim3(BIG_BLOCKS), dim3(BIG_THREADS), 0, stream, inputs, ws);
    hipLaunchKernelGGL(k_red, dim3(257), dim3(256), 0, stream, ws);
    hipLaunchKernelGGL(k_gxgh, dim3(128), dim3(256), 0, stream,
                       W_hh, b_hh, g_in, be_in, ws);
    hipLaunchKernelGGL(k_midh1, dim3(64), dim3(256), 0, stream,
                       W1, b1, g_f, be_f, ws);
    hipLaunchKernelGGL(k_ffnew, dim3(64), dim3(256), 0, stream,
                       W2, b2, out, ws);
    if (it < 2)
      hipLaunchKernelGGL(k_qkg, dim3(65), dim3(256), 0, stream,
                         noise, mu, sigma, g_s, be_s, ws, 0);
  }
}

// Round 5
// 550.990 us; speedup vs baseline: 2.4554x; 1.1517x over previous
//
#include <hip/hip_runtime.h>
#include <stdint.h>

#define B_ROWS 131072
#define SCALE 0.0625f
#define LN_EPS 1e-5f
#define ATTN_EPS 1e-8f

#define BIG_BLOCKS 512
#define BIG_THREADS 512
#define ROWS_PER_BLOCK (B_ROWS / BIG_BLOCKS)   // 256
#define ROWS_PER_WAVE  (ROWS_PER_BLOCK / 8)    // 32 (8 waves/block)
#define NSLICE BIG_BLOCKS                      // 512 partial slices

// ---- workspace layout (float offsets) ----
#define WS_PARTU 0
#define WS_PARTS (WS_PARTU + NSLICE*4096)        // 2097152
#define WS_U     (WS_PARTS + NSLICE*16)          // 2105344
#define WS_S     (WS_U + 4096)                   // 2109440
#define WS_SLOTS (WS_S + 64)                     // 2109504
#define WS_MID   (WS_SLOTS + 4096)               // 2113600
#define WS_GX    (WS_MID + 4096)                 // 2117696
#define WS_GH    (WS_GX + 12288)                 // 2129984
#define WS_H1    (WS_GH + 12288)                 // 2142272
#define WS_QKG   (WS_H1 + 4096)                  // 2146368
#define WS_QB    (WS_QKG + 4096)                 // 2150464
#define WS_WIHV  (WS_QB + 64)                    // 2150528
#define WS_BGX   (WS_WIHV + 196608)              // 2347136
#define WS_WQKG  (WS_BGX + 768)                  // 2347904
#define WS_U2G   (WS_WQKG + 65536)               // 2413440
#define WS_U1    (WS_U2G + 256)                  // 2413696
#define WS_C1    (WS_U1 + 256)                   // 2413952
// total ~2413953 floats ~ 9.66 MB

// =====================================================================
// K_pre1 (restructured for latency): 257 blocks.
//  0..191  : W_ihv rows j0=bid*4 .. +3 ; W_ih rows staged in LDS,
//            Wv streamed unroll-8; bgx via wave-parallel reduce.
//  192..255: WqkgT rows c0=(bid-192)*4 ; Wk cols staged in LDS (one
//            parallel round-trip), Wq streamed unroll-8; u2g via reduce.
//  256     : t2 = Wk·be_in + bk (per-thread float4 row stream);
//            u1 = Wq^T·t2 (coalesced + LDS broadcast); c1 via reduce.
// Old version: 81 blocks, serial broadcast loads, 0.9% VALUBusy, 103us.
// =====================================================================
__global__ __launch_bounds__(256) void k_pre1(
    const float* __restrict__ Wq, const float* __restrict__ bq,
    const float* __restrict__ Wk, const float* __restrict__ bk,
    const float* __restrict__ Wv, const float* __restrict__ bv,
    const float* __restrict__ W_ih, const float* __restrict__ b_ih,
    const float* __restrict__ g_in, const float* __restrict__ be_in,
    float* __restrict__ ws)
{
  int bid = blockIdx.x, t = threadIdx.x;
  int wave = t >> 6, lane = t & 63;
  if (bid < 192) {
    __shared__ __align__(16) float sW[4 * 256];
    __shared__ __align__(16) float sBv[256];
    int j0 = bid * 4;
#pragma unroll
    for (int r = 0; r < 4; r++) sW[r * 256 + t] = W_ih[(j0 + r) * 256 + t];
    sBv[t] = bv[t];
    __syncthreads();
    int d = t;
    float a0 = 0.f, a1 = 0.f, a2 = 0.f, a3 = 0.f;
#pragma unroll 8
    for (int dd = 0; dd < 256; dd++) {
      float v = Wv[dd * 256 + d];
      a0 = fmaf(sW[0 * 256 + dd], v, a0);
      a1 = fmaf(sW[1 * 256 + dd], v, a1);
      a2 = fmaf(sW[2 * 256 + dd], v, a2);
      a3 = fmaf(sW[3 * 256 + dd], v, a3);
    }
    ws[WS_WIHV + (j0 + 0) * 256 + d] = a0;
    ws[WS_WIHV + (j0 + 1) * 256 + d] = a1;
    ws[WS_WIHV + (j0 + 2) * 256 + d] = a2;
    ws[WS_WIHV + (j0 + 3) * 256 + d] = a3;
    // bgx[j0+wave] = b_ih + sW[wave]·bv, wave-parallel
    float s = 0.f;
#pragma unroll
    for (int q = 0; q < 4; q++) {
      int idx = lane * 4 + q;
      s = fmaf(sW[wave * 256 + idx], sBv[idx], s);
    }
#pragma unroll
    for (int m = 1; m <= 32; m <<= 1) s += __shfl_xor(s, m);
    if (lane == 0) ws[WS_BGX + j0 + wave] = b_ih[j0 + wave] + s;
  } else if (bid < 256) {
    __shared__ __align__(16) float sKc[4 * 256];
    __shared__ __align__(16) float sBq[256];
    int c0 = (bid - 192) * 4;
#pragma unroll
    for (int r = 0; r < 4; r++) sKc[r * 256 + t] = Wk[t * 256 + c0 + r];
    sBq[t] = bq[t];
    __syncthreads();
    int d = t;
    float a0 = 0.f, a1 = 0.f, a2 = 0.f, a3 = 0.f;
#pragma unroll 8
    for (int i = 0; i < 256; i++) {
      float wq = Wq[i * 256 + d];
      a0 = fmaf(wq, sKc[0 * 256 + i], a0);
      a1 = fmaf(wq, sKc[1 * 256 + i], a1);
      a2 = fmaf(wq, sKc[2 * 256 + i], a2);
      a3 = fmaf(wq, sKc[3 * 256 + i], a3);
    }
    ws[WS_WQKG + (c0 + 0) * 256 + d] = SCALE * g_in[c0 + 0] * a0;
    ws[WS_WQKG + (c0 + 1) * 256 + d] = SCALE * g_in[c0 + 1] * a1;
    ws[WS_WQKG + (c0 + 2) * 256 + d] = SCALE * g_in[c0 + 2] * a2;
    ws[WS_WQKG + (c0 + 3) * 256 + d] = SCALE * g_in[c0 + 3] * a3;
    // u2g[c0+wave] = SCALE*g_in*(bq·Wk[:,c0+wave]), wave-parallel
    float s = 0.f;
#pragma unroll
    for (int q = 0; q < 4; q++) {
      int idx = lane * 4 + q;
      s = fmaf(sBq[idx], sKc[wave * 256 + idx], s);
    }
#pragma unroll
    for (int m = 1; m <= 32; m <<= 1) s += __shfl_xor(s, m);
    if (lane == 0) ws[WS_U2G + c0 + wave] = SCALE * g_in[c0 + wave] * s;
  } else {
    __shared__ __align__(16) float sBe[256];
    __shared__ __align__(16) float sT2[256];
    sBe[t] = be_in[t];
    __syncthreads();
    // t2[t] = Wk[t]·be_in + bk[t]  (per-thread row stream, float4)
    float a = 0.f;
#pragma unroll 8
    for (int dp = 0; dp < 256; dp += 4) {
      float4 w = *(const float4*)(Wk + t * 256 + dp);
      a = fmaf(w.x, sBe[dp], fmaf(w.y, sBe[dp + 1],
          fmaf(w.z, sBe[dp + 2], fmaf(w.w, sBe[dp + 3], a))));
    }
    sT2[t] = a + bk[t];
    __syncthreads();
    // u1[t] = sum_i Wq[i][t] * t2[i]
    float u = 0.f;
#pragma unroll 8
    for (int i = 0; i < 256; i++)
      u = fmaf(Wq[i * 256 + t], sT2[i], u);
    ws[WS_U1 + t] = u;
    // c1 = bq·t2, wave 0 parallel reduce
    if (wave == 0) {
      float s = 0.f;
#pragma unroll
      for (int q = 0; q < 4; q++) {
        int idx = lane * 4 + q;
        s = fmaf(bq[idx], sT2[idx], s);
      }
#pragma unroll
      for (int m = 1; m <= 32; m <<= 1) s += __shfl_xor(s, m);
      if (lane == 0) ws[WS_C1] = s;
    }
  }
}

// =====================================================================
// K_qkg: s = LN(slots, g_s, be_s);  qkg[n][c] = s[n]·WqkgT[c] + u2g[c]
//        qb[n] = SCALE*(s[n]·u1 + c1).  init: slots = mu + sigma*noise.
// =====================================================================
__global__ __launch_bounds__(256) void k_qkg(
    const float* __restrict__ noise, const float* __restrict__ mu,
    const float* __restrict__ sigma, const float* __restrict__ g_s,
    const float* __restrict__ be_s, float* __restrict__ ws, int init)
{
  __shared__ __align__(16) float sS[16 * 260];
  __shared__ __align__(16) float sAux[512];
  __shared__ __align__(16) float sStat[32];
  int bid = blockIdx.x, t = threadIdx.x;
  for (int n = 0; n < 16; n++) {
    float v;
    if (init) v = fmaf(sigma[t], noise[n * 256 + t], mu[t]);
    else      v = ws[WS_SLOTS + n * 256 + t];
    sS[n * 260 + t] = v;
    if (init && bid == 0) ws[WS_SLOTS + n * 256 + t] = v;
  }
  __syncthreads();
  { int n = t >> 4, c = t & 15;
    float s1 = 0.f, s2 = 0.f;
    for (int k = 0; k < 16; k++) {
      float x = sS[n * 260 + c * 16 + k];
      s1 += x; s2 = fmaf(x, x, s2);
    }
    sAux[n * 16 + c] = s1; sAux[256 + n * 16 + c] = s2; }
  __syncthreads();
  if (t < 16) {
    float s1 = 0.f, s2 = 0.f;
    for (int c = 0; c < 16; c++) { s1 += sAux[t * 16 + c]; s2 += sAux[256 + t * 16 + c]; }
    float m = s1 * (1.f / 256.f);
    float v = fmaxf(fmaf(-m, m, s2 * (1.f / 256.f)), 0.f);
    sStat[t] = m; sStat[16 + t] = rsqrtf(v + LN_EPS);
  }
  __syncthreads();
  { float gs = g_s[t], bs = be_s[t];
    for (int n = 0; n < 16; n++) {
      float m = sStat[n], rs = sStat[16 + n];
      sS[n * 260 + t] = fmaf((sS[n * 260 + t] - m) * rs, gs, bs);
    } }
  __syncthreads();
  if (bid < 64) {
    int cr = t >> 6, n = (t >> 2) & 15, ks = t & 3;
    int c = bid * 4 + cr;
    const float* wrow = ws + WS_WQKG + c * 256 + ks * 64;
    const float* srow = &sS[n * 260 + ks * 64];
    float acc = 0.f;
#pragma unroll
    for (int i = 0; i < 16; i++) {
      float4 w = *(const float4*)(wrow + i * 4);
      float4 s4 = *(const float4*)(srow + i * 4);
      acc = fmaf(w.x, s4.x, fmaf(w.y, s4.y, fmaf(w.z, s4.z, fmaf(w.w, s4.w, acc))));
    }
    sAux[t] = acc;
    __syncthreads();
    if (t < 64) {
      int cr2 = t >> 4, n2 = t & 15;
      int c2 = bid * 4 + cr2;
      int b = cr2 * 64 + n2 * 4;
      float s = sAux[b] + sAux[b + 1] + sAux[b + 2] + sAux[b + 3];
      ws[WS_QKG + n2 * 256 + c2] = s + ws[WS_U2G + c2];
    }
  } else {
    int n = t >> 4, ks = t & 15;
    float acc = 0.f;
    for (int k = 0; k < 16; k++)
      acc = fmaf(sS[n * 260 + ks * 16 + k], ws[WS_U1 + ks * 16 + k], acc);
    sAux[t] = acc;
    __syncthreads();
    if (t < 16) {
      float s = 0.f;
      for (int k = 0; k < 16; k++) s += sAux[t * 16 + k];
      ws[WS_QB + t] = SCALE * (s + ws[WS_C1]);
    }
  }
}

// =====================================================================
// K_big: 512 threads, 8 waves, 32 rows/wave, processed as 16 row-PAIRS.
// Two independent dependency chains per wave (4 per SIMD) hide the
// serial shuffle-reduce latency. P/qw shared across the pair.
// (512,2): VGPR budget 256; (512,4) = 64-reg cap spilled. Occupancy
// is structurally 2 waves/SIMD (V+A > 128).
// =====================================================================
__global__ __launch_bounds__(512, 2) void k_big(
    const float* __restrict__ X, float* __restrict__ ws)
{
  __shared__ __align__(16) float red[4 * 4096];   // 64 KB
  __shared__ __align__(16) float redS[128];       // 8 waves x 16
  int t = threadIdx.x;
  int wave = t >> 6, lane = t & 63;
  int p = lane >> 4, g = lane & 15;

  const float* qkg = ws + WS_QKG;
  float qw[4][16];
  float qs[4];
#pragma unroll
  for (int i = 0; i < 4; i++) {
    const float* rp = qkg + (4 * p + i) * 256 + g * 16;
#pragma unroll
    for (int jq = 0; jq < 4; jq++) {
      float4 v4 = *(const float4*)(rp + 4 * jq);
      qw[i][4 * jq + 0] = v4.x; qw[i][4 * jq + 1] = v4.y;
      qw[i][4 * jq + 2] = v4.z; qw[i][4 * jq + 3] = v4.w;
    }
    float s = 0.f;
#pragma unroll
    for (int j = 0; j < 16; j++) s += qw[i][j];
    qs[i] = s;
  }
#pragma unroll
  for (int m = 1; m <= 8; m <<= 1) {
#pragma unroll
    for (int i = 0; i < 4; i++) qs[i] += __shfl_xor(qs[i], m);
  }
  float qb0[4];
  {
    float4 q4 = *(const float4*)(ws + WS_QB + 4 * p);
    qb0[0] = q4.x; qb0[1] = q4.y; qb0[2] = q4.z; qb0[3] = q4.w;
  }

  float P[4][16];
#pragma unroll
  for (int i = 0; i < 4; i++)
#pragma unroll
    for (int j = 0; j < 16; j++) P[i][j] = 0.f;
  float Q[4] = {0.f, 0.f, 0.f, 0.f};
  float Sa[4] = {0.f, 0.f, 0.f, 0.f};

  size_t rowbase = (size_t)blockIdx.x * ROWS_PER_BLOCK + (size_t)wave * ROWS_PER_WAVE;
  const float* base = X + rowbase * 256 + g * 16;

  float4 cA0 = *(const float4*)(base + 0);
  float4 cB0 = *(const float4*)(base + 4);
  float4 cC0 = *(const float4*)(base + 8);
  float4 cD0 = *(const float4*)(base + 12);
  float4 cA1 = *(const float4*)(base + 256);
  float4 cB1 = *(const float4*)(base + 260);
  float4 cC1 = *(const float4*)(base + 264);
  float4 cD1 = *(const float4*)(base + 268);

#pragma unroll 1
  for (int r = 0; r < ROWS_PER_WAVE; r += 2) {
    const float* nx = base + (size_t)((r + 2 < ROWS_PER_WAVE) ? (r + 2) : 0) * 256;
    float4 pA0 = *(const float4*)(nx + 0);
    float4 pB0 = *(const float4*)(nx + 4);
    float4 pC0 = *(const float4*)(nx + 8);
    float4 pD0 = *(const float4*)(nx + 12);
    float4 pA1 = *(const float4*)(nx + 256);
    float4 pB1 = *(const float4*)(nx + 260);
    float4 pC1 = *(const float4*)(nx + 264);
    float4 pD1 = *(const float4*)(nx + 268);

    float x0[16], x1[16];
    x0[0] = cA0.x; x0[1] = cA0.y; x0[2] = cA0.z; x0[3] = cA0.w;
    x0[4] = cB0.x; x0[5] = cB0.y; x0[6] = cB0.z; x0[7] = cB0.w;
    x0[8] = cC0.x; x0[9] = cC0.y; x0[10] = cC0.z; x0[11] = cC0.w;
    x0[12] = cD0.x; x0[13] = cD0.y; x0[14] = cD0.z; x0[15] = cD0.w;
    x1[0] = cA1.x; x1[1] = cA1.y; x1[2] = cA1.z; x1[3] = cA1.w;
    x1[4] = cB1.x; x1[5] = cB1.y; x1[6] = cB1.z; x1[7] = cB1.w;
    x1[8] = cC1.x; x1[9] = cC1.y; x1[10] = cC1.z; x1[11] = cC1.w;
    x1[12] = cD1.x; x1[13] = cD1.y; x1[14] = cD1.z; x1[15] = cD1.w;

    // ---- stats, both rows interleaved ----
    float s10 = 0.f, s20 = 0.f, s11 = 0.f, s21 = 0.f;
#pragma unroll
    for (int j = 0; j < 16; j++) {
      s10 += x0[j]; s20 = fmaf(x0[j], x0[j], s20);
      s11 += x1[j]; s21 = fmaf(x1[j], x1[j], s21);
    }
#pragma unroll
    for (int m = 1; m <= 8; m <<= 1) {
      s10 += __shfl_xor(s10, m); s11 += __shfl_xor(s11, m);
      s20 += __shfl_xor(s20, m); s21 += __shfl_xor(s21, m);
    }
    float mean0 = s10 * (1.f / 256.f), mean1 = s11 * (1.f / 256.f);
    float var0 = fmaxf(fmaf(-mean0, mean0, s20 * (1.f / 256.f)), 0.f);
    float var1 = fmaxf(fmaf(-mean1, mean1, s21 * (1.f / 256.f)), 0.f);
    float rs0 = rsqrtf(var0 + LN_EPS), rs1 = rsqrtf(var1 + LN_EPS);
    float mrs0 = mean0 * rs0, mrs1 = mean1 * rs1;

    // ---- dots, both rows interleaved ----
    float d0[4] = {0.f, 0.f, 0.f, 0.f};
    float d1[4] = {0.f, 0.f, 0.f, 0.f};
#pragma unroll
    for (int j = 0; j < 16; j++) {
#pragma unroll
      for (int i = 0; i < 4; i++) {
        d0[i] = fmaf(qw[i][j], x0[j], d0[i]);
        d1[i] = fmaf(qw[i][j], x1[j], d1[i]);
      }
    }
#pragma unroll
    for (int m = 1; m <= 8; m <<= 1) {
#pragma unroll
      for (int i = 0; i < 4; i++) {
        d0[i] += __shfl_xor(d0[i], m);
        d1[i] += __shfl_xor(d1[i], m);
      }
    }
    float dsc0[4], dsc1[4];
#pragma unroll
    for (int i = 0; i < 4; i++) {
      dsc0[i] = fmaf(rs0, d0[i], fmaf(-mrs0, qs[i], qb0[i]));
      dsc1[i] = fmaf(rs1, d1[i], fmaf(-mrs1, qs[i], qb0[i]));
    }

    // ---- softmax, both rows interleaved ----
    float mx0 = fmaxf(fmaxf(dsc0[0], dsc0[1]), fmaxf(dsc0[2], dsc0[3]));
    float mx1 = fmaxf(fmaxf(dsc1[0], dsc1[1]), fmaxf(dsc1[2], dsc1[3]));
    mx0 = fmaxf(mx0, __shfl_xor(mx0, 16)); mx1 = fmaxf(mx1, __shfl_xor(mx1, 16));
    mx0 = fmaxf(mx0, __shfl_xor(mx0, 32)); mx1 = fmaxf(mx1, __shfl_xor(mx1, 32));
    float e0[4], e1[4];
#pragma unroll
    for (int i = 0; i < 4; i++) {
      e0[i] = __expf(dsc0[i] - mx0);
      e1[i] = __expf(dsc1[i] - mx1);
    }
    float se0 = e0[0] + e0[1] + e0[2] + e0[3];
    float se1 = e1[0] + e1[1] + e1[2] + e1[3];
    se0 += __shfl_xor(se0, 16); se1 += __shfl_xor(se1, 16);
    se0 += __shfl_xor(se0, 32); se1 += __shfl_xor(se1, 32);
    float inv0 = 1.0f / se0, inv1 = 1.0f / se1;
    float a0v[4], ar0[4], a1v[4], ar1[4];
#pragma unroll
    for (int i = 0; i < 4; i++) {
      a0v[i] = fmaf(e0[i], inv0, ATTN_EPS); ar0[i] = a0v[i] * rs0;
      a1v[i] = fmaf(e1[i], inv1, ATTN_EPS); ar1[i] = a1v[i] * rs1;
    }

    // ---- P accumulation (shared accumulators, row r then r+1) ----
#pragma unroll
    for (int j = 0; j < 16; j++) {
#pragma unroll
      for (int i = 0; i < 4; i++) {
        P[i][j] = fmaf(ar0[i], x0[j], P[i][j]);
        P[i][j] = fmaf(ar1[i], x1[j], P[i][j]);
      }
    }
#pragma unroll
    for (int i = 0; i < 4; i++) {
      Q[i] = fmaf(a0v[i], mrs0, Q[i]);
      Q[i] = fmaf(a1v[i], mrs1, Q[i]);
      Sa[i] += a0v[i];
      Sa[i] += a1v[i];
    }

    cA0 = pA0; cB0 = pB0; cC0 = pC0; cD0 = pD0;
    cA1 = pA1; cB1 = pB1; cC1 = pC1; cD1 = pD1;
  }

  // Two-stage cross-wave reduce in 64KB LDS (Uy = P - Q per slot/elem).
  int slot = wave & 3;
  if (wave < 4) {
#pragma unroll
    for (int i = 0; i < 4; i++) {
#pragma unroll
      for (int jq = 0; jq < 4; jq++) {
        float4 v4;
        v4.x = P[i][4 * jq + 0] - Q[i]; v4.y = P[i][4 * jq + 1] - Q[i];
        v4.z = P[i][4 * jq + 2] - Q[i]; v4.w = P[i][4 * jq + 3] - Q[i];
        *(float4*)&red[slot * 4096 + (4 * p + i) * 256 + g * 16 + jq * 4] = v4;
      }
    }
  }
  if (g == 0) {
#pragma unroll
    for (int i = 0; i < 4; i++) redS[wave * 16 + 4 * p + i] = Sa[i];
  }
  __syncthreads();
  if (wave >= 4) {
#pragma unroll
    for (int i = 0; i < 4; i++) {
#pragma unroll
      for (int jq = 0; jq < 4; jq++) {
        float4* dst = (float4*)&red[slot * 4096 + (4 * p + i) * 256 + g * 16 + jq * 4];
        float4 c = *dst;
        c.x += P[i][4 * jq + 0] - Q[i]; c.y += P[i][4 * jq + 1] - Q[i];
        c.z += P[i][4 * jq + 2] - Q[i]; c.w += P[i][4 * jq + 3] - Q[i];
        *dst = c;
      }
    }
  }
  __syncthreads();
#pragma unroll
  for (int k = 0; k < 8; k++) {
    int idx = k * 512 + t;
    float v = red[idx] + red[4096 + idx] + red[8192 + idx] + red[12288 + idx];
    ws[WS_PARTU + (size_t)blockIdx.x * 4096 + idx] = v;
  }
  if (t < 16) {
    float sv = 0.f;
#pragma unroll
    for (int w = 0; w < 8; w++) sv += redS[w * 16 + t];
    ws[WS_PARTS + blockIdx.x * 16 + t] = sv;
  }
}

// =====================================================================
// K_red: reduce 512 partial slices -> U[16][256], S[16]
// =====================================================================
__global__ __launch_bounds__(256) void k_red(float* __restrict__ ws)
{
  __shared__ __align__(16) float sAux[256];
  int bid = blockIdx.x, t = threadIdx.x;
  if (bid < 256) {
    int el = t & 15, wg = t >> 4;
    int e = bid * 16 + el;
    float acc = 0.f;
#pragma unroll 8
    for (int k = 0; k < 32; k++)
      acc += ws[WS_PARTU + (size_t)(wg + k * 16) * 4096 + e];
    sAux[t] = acc;
    __syncthreads();
    if (t < 16) {
      float s = 0.f;
      for (int w = 0; w < 16; w++) s += sAux[w * 16 + t];
      ws[WS_U + bid * 16 + t] = s;
    }
  } else {
    int n = t & 15, wg = t >> 4;
    float acc = 0.f;
#pragma unroll 8
    for (int k = 0; k < 32; k++)
      acc += ws[WS_PARTS + (wg + k * 16) * 16 + n];
    sAux[t] = acc;
    __syncthreads();
    if (t < 16) {
      float s = 0.f;
      for (int w = 0; w < 16; w++) s += sAux[w * 16 + t];
      ws[WS_S + t] = s;
    }
  }
}

// =====================================================================
// K_gxgh: bid<64:  gx[n][j] = W_ihv[j]·(g_in*(U[n]/S[n]) + be_in) + bgx[j]
//         bid>=64: gh[n][j] = W_hh[j]·slots_prev[n] + b_hh[j]
// =====================================================================
__global__ __launch_bounds__(256) void k_gxgh(
    const float* __restrict__ W_hh, const float* __restrict__ b_hh,
    const float* __restrict__ g_in, const float* __restrict__ be_in,
    float* __restrict__ ws)
{
  __shared__ __align__(16) float sU[16 * 260];
  __shared__ __align__(16) float sInv[16];
  int bid = blockIdx.x, t = threadIdx.x;
  bool isgx = bid < 64;
  if (isgx && t < 16) sInv[t] = 1.0f / ws[WS_S + t];
  __syncthreads();
  if (isgx) {
    float gi = g_in[t], bi = be_in[t];
    for (int n = 0; n < 16; n++)
      sU[n * 260 + t] = fmaf(gi * ws[WS_U + n * 256 + t], sInv[n], bi);
  } else {
    for (int n = 0; n < 16; n++)
      sU[n * 260 + t] = ws[WS_SLOTS + n * 256 + t];
  }
  __syncthreads();
  int jr = t >> 4, n = t & 15;
  if (jr < 12) {
    int j = (isgx ? bid : bid - 64) * 12 + jr;
    const float* srow = &sU[n * 260];
    const float* wrow = isgx ? (ws + WS_WIHV + j * 256) : (W_hh + j * 256);
    float acc = isgx ? ws[WS_BGX + j] : b_hh[j];
#pragma unroll 8
    for (int k = 0; k < 64; k++) {
      float4 w = *(const float4*)(wrow + k * 4);
      float4 s4 = *(const float4*)(srow + k * 4);
      acc = fmaf(w.x, s4.x, fmaf(w.y, s4.y, fmaf(w.z, s4.z, fmaf(w.w, s4.w, acc))));
    }
    if (isgx) ws[WS_GX + n * 768 + j] = acc;
    else      ws[WS_GH + n * 768 + j] = acc;
  }
}

// =====================================================================
// K_midh1: GRU gates -> slots_mid; LN(g_f,be_f); h1 = relu(lnf@W1.T + b1)
// =====================================================================
__global__ __launch_bounds__(256) void k_midh1(
    const float* __restrict__ W1, const float* __restrict__ b1,
    const float* __restrict__ g_f, const float* __restrict__ be_f,
    float* __restrict__ ws)
{
  __shared__ __align__(16) float sM[16 * 260];
  __shared__ __align__(16) float sAux[512];
  __shared__ __align__(16) float sStat[32];
  int bid = blockIdx.x, t = threadIdx.x;
  for (int n = 0; n < 16; n++) {
    float xr = ws[WS_GX + n * 768 + t],       hr = ws[WS_GH + n * 768 + t];
    float xz = ws[WS_GX + n * 768 + 256 + t], hz = ws[WS_GH + n * 768 + 256 + t];
    float xn = ws[WS_GX + n * 768 + 512 + t], hn = ws[WS_GH + n * 768 + 512 + t];
    float sp = ws[WS_SLOTS + n * 256 + t];
    float r = 1.f / (1.f + __expf(-(xr + hr)));
    float z = 1.f / (1.f + __expf(-(xz + hz)));
    float nn = tanhf(fmaf(r, hn, xn));
    float mid = fmaf(z, sp - nn, nn);
    sM[n * 260 + t] = mid;
    if (bid == 0) ws[WS_MID + n * 256 + t] = mid;
  }
  __syncthreads();
  { int n = t >> 4, c = t & 15;
    float s1 = 0.f, s2 = 0.f;
    for (int k = 0; k < 16; k++) {
      float x = sM[n * 260 + c * 16 + k];
      s1 += x; s2 = fmaf(x, x, s2);
    }
    sAux[n * 16 + c] = s1; sAux[256 + n * 16 + c] = s2; }
  __syncthreads();
  if (t < 16) {
    float s1 = 0.f, s2 = 0.f;
    for (int c = 0; c < 16; c++) { s1 += sAux[t * 16 + c]; s2 += sAux[256 + t * 16 + c]; }
    float m = s1 * (1.f / 256.f);
    float v = fmaxf(fmaf(-m, m, s2 * (1.f / 256.f)), 0.f);
    sStat[t] = m; sStat[16 + t] = rsqrtf(v + LN_EPS);
  }
  __syncthreads();
  { float gf = g_f[t], bf = be_f[t];
    for (int n = 0; n < 16; n++) {
      float m = sStat[n], rs = sStat[16 + n];
      sM[n * 260 + t] = fmaf((sM[n * 260 + t] - m) * rs, gf, bf);
    } }
  __syncthreads();
  int jr = t >> 6, n = (t >> 2) & 15, ks = t & 3;
  int j = bid * 4 + jr;
  const float* wrow = W1 + j * 256 + ks * 64;
  const float* srow = &sM[n * 260 + ks * 64];
  float acc = 0.f;
#pragma unroll
  for (int k = 0; k < 16; k++) {
    float4 w = *(const float4*)(wrow + k * 4);
    float4 s4 = *(const float4*)(srow + k * 4);
    acc = fmaf(w.x, s4.x, fmaf(w.y, s4.y, fmaf(w.z, s4.z, fmaf(w.w, s4.w, acc))));
  }
  sAux[t] = acc;
  __syncthreads();
  if (t < 64) {
    int jr2 = t >> 4, n2 = t & 15;
    int j2 = bid * 4 + jr2;
    int b = jr2 * 64 + n2 * 4;
    float s = sAux[b] + sAux[b + 1] + sAux[b + 2] + sAux[b + 3] + b1[j2];
    ws[WS_H1 + n2 * 256 + j2] = fmaxf(s, 0.f);
  }
}

// =====================================================================
// K_ffnew: ff = h1@W2.T + b2;  slots_new = slots_mid + ff -> ws.slots, d_out
// =====================================================================
__global__ __launch_bounds__(256) void k_ffnew(
    const float* __restrict__ W2, const float* __restrict__ b2v,
    float* __restrict__ out, float* __restrict__ ws)
{
  __shared__ __align__(16) float sH[16 * 260];
  __shared__ __align__(16) float sAux[256];
  int bid = blockIdx.x, t = threadIdx.x;
  for (int n = 0; n < 16; n++)
    sH[n * 260 + t] = ws[WS_H1 + n * 256 + t];
  __syncthreads();
  int dr = t >> 6, n = (t >> 2) & 15, ks = t & 3;
  int d = bid * 4 + dr;
  const float* wrow = W2 + d * 256 + ks * 64;
  const float* srow = &sH[n * 260 + ks * 64];
  float acc = 0.f;
#pragma unroll
  for (int k = 0; k < 16; k++) {
    float4 w = *(const float4*)(wrow + k * 4);
    float4 s4 = *(const float4*)(srow + k * 4);
    acc = fmaf(w.x, s4.x, fmaf(w.y, s4.y, fmaf(w.z, s4.z, fmaf(w.w, s4.w, acc))));
  }
  sAux[t] = acc;
  __syncthreads();
  if (t < 64) {
    int dr2 = t >> 4, n2 = t & 15;
    int d2 = bid * 4 + dr2;
    int b = dr2 * 64 + n2 * 4;
    float s = sAux[b] + sAux[b + 1] + sAux[b + 2] + sAux[b + 3]
            + b2v[d2] + ws[WS_MID + n2 * 256 + d2];
    ws[WS_SLOTS + n2 * 256 + d2] = s;
    out[n2 * 256 + d2] = s;
  }
}

// =====================================================================
extern "C" void kernel_launch(void* const* d_in, const int* in_sizes, int n_in,
                              void* d_out, int out_size, void* d_ws, size_t ws_size,
                              hipStream_t stream)
{
  (void)in_sizes; (void)n_in; (void)out_size; (void)ws_size;
  const float* inputs = (const float*)d_in[0];
  const float* noise  = (const float*)d_in[1];
  const float* mu     = (const float*)d_in[2];
  const float* sigma  = (const float*)d_in[3];
  const float* Wq     = (const float*)d_in[4];
  const float* bq     = (const float*)d_in[5];
  const float* Wk     = (const float*)d_in[6];
  const float* bk     = (const float*)d_in[7];
  const float* Wv     = (const float*)d_in[8];
  const float* bv     = (const float*)d_in[9];
  const float* W_ih   = (const float*)d_in[10];
  const float* W_hh   = (const float*)d_in[11];
  const float* b_ih   = (const float*)d_in[12];
  const float* b_hh   = (const float*)d_in[13];
  const float* W1     = (const float*)d_in[14];
  const float* b1     = (const float*)d_in[15];
  const float* W2     = (const float*)d_in[16];
  const float* b2     = (const float*)d_in[17];
  const float* g_in   = (const float*)d_in[18];
  const float* be_in  = (const float*)d_in[19];
  const float* g_s    = (const float*)d_in[20];
  const float* be_s   = (const float*)d_in[21];
  const float* g_f    = (const float*)d_in[22];
  const float* be_f   = (const float*)d_in[23];
  float* ws = (float*)d_ws;
  float* out = (float*)d_out;

  hipLaunchKernelGGL(k_pre1, dim3(257), dim3(256), 0, stream,
                     Wq, bq, Wk, bk, Wv, bv, W_ih, b_ih, g_in, be_in, ws);
  hipLaunchKernelGGL(k_qkg, dim3(65), dim3(256), 0, stream,
                     noise, mu, sigma, g_s, be_s, ws, 1);
  for (int it = 0; it < 3; it++) {
    hipLaunchKernelGGL(k_big, dim3(BIG_BLOCKS), dim3(BIG_THREADS), 0, stream, inputs, ws);
    hipLaunchKernelGGL(k_red, dim3(257), dim3(256), 0, stream, ws);
    hipLaunchKernelGGL(k_gxgh, dim3(128), dim3(256), 0, stream,
                       W_hh, b_hh, g_in, be_in, ws);
    hipLaunchKernelGGL(k_midh1, dim3(64), dim3(256), 0, stream,
                       W1, b1, g_f, be_f, ws);
    hipLaunchKernelGGL(k_ffnew, dim3(64), dim3(256), 0, stream,
                       W2, b2, out, ws);
    if (it < 2)
      hipLaunchKernelGGL(k_qkg, dim3(65), dim3(256), 0, stream,
                         noise, mu, sigma, g_s, be_s, ws, 0);
  }
}